// Round 3
// baseline (891.819 us; speedup 1.0000x reference)
//
#include <hip/hip_runtime.h>

#define NT 256

__device__ __forceinline__ float fast_tanh(float x) {
  float cl = fminf(fmaxf(x, -15.f), 15.f);
  float e = __builtin_amdgcn_exp2f(cl * 2.885390081777927f);  // exp(2x)
  return (e - 1.f) * __builtin_amdgcn_rcpf(e + 1.f);
}

__device__ __forceinline__ unsigned int pack2_bf16(float a, float b) {
  unsigned int ua = __float_as_uint(a);
  unsigned int ub = __float_as_uint(b);
  ua = (ua + 0x7fffu + ((ua >> 16) & 1u)) >> 16;
  ub = (ub + 0x7fffu + ((ub >> 16) & 1u)) & 0xffff0000u;
  return ua | ub;
}

// d_hat global layout (int4 units): [b][jj(6)][i(30)][jt(5)][ht(4)]
//   addr = b*3600 + jj*600 + (i*5 + jt)*4 + ht
// Kernel A task order (ht fastest, then jt, then i) => consecutive lanes write
// consecutive int4s => fully coalesced wave stores.

// ---------------------------------------------------------------------------
// Kernel A: d_hat[i][j][h] = D[b,i,j,:] @ df_w + df_b  (bf16 to global)
// Small LDS (7.3 KB) -> 4 blocks/CU, 16 waves/CU.
// ---------------------------------------------------------------------------
__global__ __launch_bounds__(NT, 4) void mdtnn_phaseA(
    const float* __restrict__ Dg, const int* __restrict__ sizesg,
    const float* __restrict__ dfwg, const float* __restrict__ dfbg,
    int4* __restrict__ dhg)
{
  const int b = blockIdx.x;
  const int tid = threadIdx.x;
  const int n = sizesg[b];
  const int njt = (n + 5) / 6;

  __shared__ __align__(16) float dfwT[32][56];   // transposed df_w, zero-padded
  __shared__ float dfb_s[32];

  for (int t = tid; t < 32 * 56; t += NT) {
    int h = t / 56, g = t - h * 56;
    dfwT[h][g] = (h < 30) ? dfwg[g * 30 + h] : 0.f;
  }
  if (tid < 32) dfb_s[tid] = (tid < 30) ? dfbg[tid] : 0.f;
  __syncthreads();

  const int tasks = n * njt * 4;       // (i, j-tile of 6, h-tile of 8)
  for (int task = tid; task < tasks; task += NT) {
    const int ht = task & 3;
    const int tmp = task >> 2;
    const int jt = tmp % njt;
    const int i = tmp / njt;
    const int j0 = jt * 6;
    const float* Dp = Dg + (((size_t)b * 30 + i) * 30 + j0) * 56;
    float acc[6][8];
    #pragma unroll
    for (int jj = 0; jj < 6; ++jj)
      #pragma unroll
      for (int hh = 0; hh < 8; ++hh) acc[jj][hh] = 0.f;

    #pragma unroll 2
    for (int gc = 0; gc < 14; ++gc) {
      float4 dj[6];
      #pragma unroll
      for (int jj = 0; jj < 6; ++jj)
        dj[jj] = *reinterpret_cast<const float4*>(Dp + jj * 56 + gc * 4);
      #pragma unroll
      for (int hh = 0; hh < 8; ++hh) {
        float4 w = *reinterpret_cast<const float4*>(&dfwT[ht * 8 + hh][gc * 4]);
        #pragma unroll
        for (int jj = 0; jj < 6; ++jj) {
          acc[jj][hh] = fmaf(dj[jj].x, w.x, acc[jj][hh]);
          acc[jj][hh] = fmaf(dj[jj].y, w.y, acc[jj][hh]);
          acc[jj][hh] = fmaf(dj[jj].z, w.z, acc[jj][hh]);
          acc[jj][hh] = fmaf(dj[jj].w, w.w, acc[jj][hh]);
        }
      }
    }
    // coalesced stores: consecutive tasks (lanes) -> consecutive int4
    int4* outp = dhg + (size_t)b * 3600 + (i * 5 + jt) * 4 + ht;
    #pragma unroll
    for (int jj = 0; jj < 6; ++jj) {
      int4 pk;
      pk.x = (int)pack2_bf16(acc[jj][0] + dfb_s[ht * 8 + 0], acc[jj][1] + dfb_s[ht * 8 + 1]);
      pk.y = (int)pack2_bf16(acc[jj][2] + dfb_s[ht * 8 + 2], acc[jj][3] + dfb_s[ht * 8 + 3]);
      pk.z = (int)pack2_bf16(acc[jj][4] + dfb_s[ht * 8 + 4], acc[jj][5] + dfb_s[ht * 8 + 5]);
      pk.w = (int)pack2_bf16(acc[jj][6] + dfb_s[ht * 8 + 6], acc[jj][7] + dfb_s[ht * 8 + 7]);
      outp[jj * 600] = pk;
    }
  }
}

// ---------------------------------------------------------------------------
// Kernel B: 3 message-passing iterations + MLP head. 2 molecules per block
// (threads 0-127 / 128-255). LDS ~28 KB, VGPR<=128 -> 4 blocks/CU -> all
// 1024 blocks co-resident (zero tail). d_hat read from global (L3-resident).
// ---------------------------------------------------------------------------
__global__ __launch_bounds__(NT, 4) void mdtnn_phaseB(
    const int* __restrict__ Zg, const int* __restrict__ sizesg,
    const float* __restrict__ embg, const float* __restrict__ cfwg,
    const float* __restrict__ cfbg, const float* __restrict__ fcwg,
    const float* __restrict__ w1g, const float* __restrict__ b1g,
    const float* __restrict__ w2g, const float* __restrict__ b2g,
    const int4* __restrict__ dhg, float* __restrict__ outg)
{
  const int tid = threadIdx.x;
  const int m = tid >> 7;            // molecule slot 0/1
  const int lt = tid & 127;          // lane within slot
  const int b = blockIdx.x * 2 + m;
  const int n = sizesg[b];
  const int njt = (n + 5) / 6;

  __shared__ __align__(16) float cx[2][2][30][36];   // [mol][C/X1][row][cols]
  __shared__ __align__(16) float cfw_s[32][32];
  __shared__ __align__(16) float fcw_s[32][32];
  __shared__ __align__(16) float w1_s[32][16];
  __shared__ float cfb_s[32];
  __shared__ float b1_s[16];
  __shared__ float w2_s[16];
  __shared__ float wsum_s[2][2];

  for (int t = tid; t < 1024; t += NT) {
    int h = t >> 5, k = t & 31;
    bool in = (h < 30) && (k < 30);
    cfw_s[h][k] = in ? cfwg[h * 30 + k] : 0.f;
    fcw_s[h][k] = in ? fcwg[h * 30 + k] : 0.f;
  }
  for (int t = tid; t < 512; t += NT) {
    int h = t >> 4, c = t & 15;
    w1_s[h][c] = ((h < 30) && (c < 15)) ? w1g[h * 15 + c] : 0.f;
  }
  if (tid < 32) cfb_s[tid] = (tid < 30) ? cfbg[tid] : 0.f;
  if (tid < 16) {
    b1_s[tid] = (tid < 15) ? b1g[tid] : 0.f;
    w2_s[tid] = (tid < 15) ? w2g[tid] : 0.f;
  }

  // init C from embeddings
  for (int t = lt; t < n * 32; t += 128) {
    int i = t >> 5, h = t & 31;
    int z = Zg[b * 30 + i];
    cx[m][0][i][h] = (h < 30) ? embg[z * 30 + h] : 0.f;
  }
  __syncthreads();

  const int4* dhb = dhg + (size_t)b * 3600;

  for (int it = 0; it < 3; ++it) {
    // X1 = C @ cf_w + cf_b, tasks (i, kt of 8) -> 4-wide outputs
    for (int t = lt; t < n * 8; t += 128) {
      int i = t >> 3, kt = t & 7;
      float a0 = 0.f, a1 = 0.f, a2 = 0.f, a3 = 0.f;
      #pragma unroll
      for (int hc = 0; hc < 8; ++hc) {
        float4 c4 = *reinterpret_cast<const float4*>(&cx[m][0][i][hc * 4]);
        float cv[4] = {c4.x, c4.y, c4.z, c4.w};
        #pragma unroll
        for (int q = 0; q < 4; ++q) {
          float4 w = *reinterpret_cast<const float4*>(&cfw_s[hc * 4 + q][kt * 4]);
          a0 = fmaf(cv[q], w.x, a0);
          a1 = fmaf(cv[q], w.y, a1);
          a2 = fmaf(cv[q], w.z, a2);
          a3 = fmaf(cv[q], w.w, a3);
        }
      }
      float4 o = {a0 + cfb_s[kt * 4 + 0], a1 + cfb_s[kt * 4 + 1],
                  a2 + cfb_s[kt * 4 + 2], a3 + cfb_s[kt * 4 + 3]};
      *reinterpret_cast<float4*>(&cx[m][1][i][kt * 4]) = o;
    }
    __syncthreads();

    // C[j] += sum_i tanh( (X1[i] ⊙ dh[i][j]) @ fc_w )
    const int tasksB = n * njt * 4;   // (i, j-tile of 6, k-tile of 8)
    for (int task = lt; task < tasksB; task += 128) {
      const int kt = task & 3;
      const int tmp = task >> 2;
      const int jt = tmp % njt;
      const int i = tmp / njt;
      const int j0 = jt * 6;
      const int4* dhp = dhb + (i * 5 + jt) * 4;
      float acc[6][8];
      #pragma unroll
      for (int jj = 0; jj < 6; ++jj)
        #pragma unroll
        for (int kk = 0; kk < 8; ++kk) acc[jj][kk] = 0.f;

      #pragma unroll 2
      for (int hc = 0; hc < 4; ++hc) {
        int4 dv[6];
        #pragma unroll
        for (int jj = 0; jj < 6; ++jj)
          dv[jj] = dhp[jj * 600 + hc];
        float4 xa = *reinterpret_cast<const float4*>(&cx[m][1][i][hc * 8]);
        float4 xb = *reinterpret_cast<const float4*>(&cx[m][1][i][hc * 8 + 4]);
        float xh[8] = {xa.x, xa.y, xa.z, xa.w, xb.x, xb.y, xb.z, xb.w};
        #pragma unroll
        for (int hh = 0; hh < 8; ++hh) {
          float4 wa = *reinterpret_cast<const float4*>(&fcw_s[hc * 8 + hh][kt * 8]);
          float4 wb = *reinterpret_cast<const float4*>(&fcw_s[hc * 8 + hh][kt * 8 + 4]);
          #pragma unroll
          for (int jj = 0; jj < 6; ++jj) {
            unsigned int u = reinterpret_cast<const unsigned int*>(&dv[jj])[hh >> 1];
            float d = (hh & 1) ? __uint_as_float(u & 0xffff0000u)
                               : __uint_as_float(u << 16);
            float a = d * xh[hh];
            acc[jj][0] = fmaf(a, wa.x, acc[jj][0]);
            acc[jj][1] = fmaf(a, wa.y, acc[jj][1]);
            acc[jj][2] = fmaf(a, wa.z, acc[jj][2]);
            acc[jj][3] = fmaf(a, wa.w, acc[jj][3]);
            acc[jj][4] = fmaf(a, wb.x, acc[jj][4]);
            acc[jj][5] = fmaf(a, wb.y, acc[jj][5]);
            acc[jj][6] = fmaf(a, wb.z, acc[jj][6]);
            acc[jj][7] = fmaf(a, wb.w, acc[jj][7]);
          }
        }
      }
      #pragma unroll
      for (int jj = 0; jj < 6; ++jj)
        #pragma unroll
        for (int kk = 0; kk < 8; ++kk)
          atomicAdd(&cx[m][0][j0 + jj][kt * 8 + kk], fast_tanh(acc[jj][kk]));
    }
    __syncthreads();
  }

  // MLP head + masked reduce
  float e = 0.f;
  for (int t = lt; t < n * 16; t += 128) {
    int j = t >> 4, c = t & 15;
    if (c < 15) {
      float acc = 0.f;
      #pragma unroll
      for (int hc = 0; hc < 8; ++hc) {
        float4 c4 = *reinterpret_cast<const float4*>(&cx[m][0][j][hc * 4]);
        acc = fmaf(c4.x, w1_s[hc * 4 + 0][c], acc);
        acc = fmaf(c4.y, w1_s[hc * 4 + 1][c], acc);
        acc = fmaf(c4.z, w1_s[hc * 4 + 2][c], acc);
        acc = fmaf(c4.w, w1_s[hc * 4 + 3][c], acc);
      }
      e += fast_tanh(acc + b1_s[c]) * w2_s[c];
    }
  }
  #pragma unroll
  for (int off = 32; off; off >>= 1) e += __shfl_down(e, off);
  if ((tid & 63) == 0) wsum_s[m][(lt >> 6)] = e;
  __syncthreads();
  if (lt == 0) outg[b] = wsum_s[m][0] + wsum_s[m][1] + (float)n * b2g[0];
}

// ---------------------------------------------------------------------------
// Fallback (round-1 kernel, d_hat in LDS) for ws_size < 118 MB.
// ---------------------------------------------------------------------------
__global__ __launch_bounds__(NT, 2) void mdtnn_fused(
    const int* __restrict__ Zg, const float* __restrict__ Dg,
    const int* __restrict__ sizesg, const float* __restrict__ embg,
    const float* __restrict__ dfwg, const float* __restrict__ dfbg,
    const float* __restrict__ cfwg, const float* __restrict__ cfbg,
    const float* __restrict__ fcwg, const float* __restrict__ w1g,
    const float* __restrict__ b1g, const float* __restrict__ w2g,
    const float* __restrict__ b2g, float* __restrict__ outg)
{
  const int b = blockIdx.x;
  const int tid = threadIdx.x;
  const int n = sizesg[b];
  const int njt = (n + 5) / 6;

  __shared__ __align__(16) float cx[2][30][32];
  __shared__ __align__(16) float cfw_s[32][32];
  __shared__ __align__(16) float fcw_s[32][32];
  __shared__ __align__(16) float w1_s[32][16];
  __shared__ __align__(16) int4 dh2[30 * 121];
  __shared__ float dfb_s[32];
  __shared__ float cfb_s[32];
  __shared__ float b1_s[16];
  __shared__ float w2_s[16];
  __shared__ float bsum;

  float (*dfwT)[56] = reinterpret_cast<float (*)[56]>(&cx[0][0][0]);

  for (int t = tid; t < 32 * 56; t += NT) {
    int h = t / 56, g = t - h * 56;
    dfwT[h][g] = (h < 30) ? dfwg[g * 30 + h] : 0.f;
  }
  for (int t = tid; t < 1024; t += NT) {
    int h = t >> 5, k = t & 31;
    bool in = (h < 30) && (k < 30);
    cfw_s[h][k] = in ? cfwg[h * 30 + k] : 0.f;
    fcw_s[h][k] = in ? fcwg[h * 30 + k] : 0.f;
  }
  for (int t = tid; t < 512; t += NT) {
    int h = t >> 4, c = t & 15;
    w1_s[h][c] = ((h < 30) && (c < 15)) ? w1g[h * 15 + c] : 0.f;
  }
  if (tid < 32) {
    dfb_s[tid] = (tid < 30) ? dfbg[tid] : 0.f;
    cfb_s[tid] = (tid < 30) ? cfbg[tid] : 0.f;
  }
  if (tid < 16) {
    b1_s[tid] = (tid < 15) ? b1g[tid] : 0.f;
    w2_s[tid] = (tid < 15) ? w2g[tid] : 0.f;
  }
  if (tid == 0) bsum = 0.f;
  __syncthreads();

  {
    const int tasksA = n * njt * 4;
    for (int task = tid; task < tasksA; task += NT) {
      const int ht = task & 3;
      const int tmp = task >> 2;
      const int jt = tmp % njt;
      const int i = tmp / njt;
      const int j0 = jt * 6;
      const float* Dp = Dg + (((size_t)b * 30 + i) * 30 + j0) * 56;
      float acc[6][8];
      #pragma unroll
      for (int jj = 0; jj < 6; ++jj)
        #pragma unroll
        for (int hh = 0; hh < 8; ++hh) acc[jj][hh] = 0.f;
      #pragma unroll 2
      for (int gc = 0; gc < 14; ++gc) {
        float4 dj[6];
        #pragma unroll
        for (int jj = 0; jj < 6; ++jj)
          dj[jj] = *reinterpret_cast<const float4*>(Dp + jj * 56 + gc * 4);
        #pragma unroll
        for (int hh = 0; hh < 8; ++hh) {
          float4 w = *reinterpret_cast<const float4*>(&dfwT[ht * 8 + hh][gc * 4]);
          #pragma unroll
          for (int jj = 0; jj < 6; ++jj) {
            acc[jj][hh] = fmaf(dj[jj].x, w.x, acc[jj][hh]);
            acc[jj][hh] = fmaf(dj[jj].y, w.y, acc[jj][hh]);
            acc[jj][hh] = fmaf(dj[jj].z, w.z, acc[jj][hh]);
            acc[jj][hh] = fmaf(dj[jj].w, w.w, acc[jj][hh]);
          }
        }
      }
      #pragma unroll
      for (int jj = 0; jj < 6; ++jj) {
        int4 pk;
        pk.x = (int)pack2_bf16(acc[jj][0] + dfb_s[ht * 8 + 0], acc[jj][1] + dfb_s[ht * 8 + 1]);
        pk.y = (int)pack2_bf16(acc[jj][2] + dfb_s[ht * 8 + 2], acc[jj][3] + dfb_s[ht * 8 + 3]);
        pk.z = (int)pack2_bf16(acc[jj][4] + dfb_s[ht * 8 + 4], acc[jj][5] + dfb_s[ht * 8 + 5]);
        pk.w = (int)pack2_bf16(acc[jj][6] + dfb_s[ht * 8 + 6], acc[jj][7] + dfb_s[ht * 8 + 7]);
        dh2[i * 121 + ht * 30 + j0 + jj] = pk;
      }
    }
  }
  __syncthreads();

  for (int t = tid; t < n * 32; t += NT) {
    int i = t >> 5, h = t & 31;
    int z = Zg[b * 30 + i];
    cx[0][i][h] = (h < 30) ? embg[z * 30 + h] : 0.f;
  }
  __syncthreads();

  for (int it = 0; it < 3; ++it) {
    for (int task = tid; task < n * 4; task += NT) {
      int i = task >> 2, kt = task & 3;
      float acc[8];
      #pragma unroll
      for (int kk = 0; kk < 8; ++kk) acc[kk] = 0.f;
      #pragma unroll
      for (int hc = 0; hc < 8; ++hc) {
        float4 c4 = *reinterpret_cast<const float4*>(&cx[0][i][hc * 4]);
        float cv[4] = {c4.x, c4.y, c4.z, c4.w};
        #pragma unroll
        for (int q = 0; q < 4; ++q) {
          float4 wa = *reinterpret_cast<const float4*>(&cfw_s[hc * 4 + q][kt * 8]);
          float4 wb = *reinterpret_cast<const float4*>(&cfw_s[hc * 4 + q][kt * 8 + 4]);
          acc[0] = fmaf(cv[q], wa.x, acc[0]);
          acc[1] = fmaf(cv[q], wa.y, acc[1]);
          acc[2] = fmaf(cv[q], wa.z, acc[2]);
          acc[3] = fmaf(cv[q], wa.w, acc[3]);
          acc[4] = fmaf(cv[q], wb.x, acc[4]);
          acc[5] = fmaf(cv[q], wb.y, acc[5]);
          acc[6] = fmaf(cv[q], wb.z, acc[6]);
          acc[7] = fmaf(cv[q], wb.w, acc[7]);
        }
      }
      #pragma unroll
      for (int kk = 0; kk < 8; ++kk)
        cx[1][i][kt * 8 + kk] = acc[kk] + cfb_s[kt * 8 + kk];
    }
    __syncthreads();

    const int tasksB = n * njt * 4;
    for (int task = tid; task < tasksB; task += NT) {
      const int kt = task & 3;
      const int tmp = task >> 2;
      const int jt = tmp % njt;
      const int i = tmp / njt;
      const int j0 = jt * 6;
      float acc[6][8];
      #pragma unroll
      for (int jj = 0; jj < 6; ++jj)
        #pragma unroll
        for (int kk = 0; kk < 8; ++kk) acc[jj][kk] = 0.f;
      #pragma unroll 1
      for (int hc = 0; hc < 4; ++hc) {
        int4 dv[6];
        #pragma unroll
        for (int jj = 0; jj < 6; ++jj)
          dv[jj] = dh2[i * 121 + hc * 30 + j0 + jj];
        float4 xa = *reinterpret_cast<const float4*>(&cx[1][i][hc * 8]);
        float4 xb = *reinterpret_cast<const float4*>(&cx[1][i][hc * 8 + 4]);
        float xh[8] = {xa.x, xa.y, xa.z, xa.w, xb.x, xb.y, xb.z, xb.w};
        #pragma unroll
        for (int hh = 0; hh < 8; ++hh) {
          float4 wa = *reinterpret_cast<const float4*>(&fcw_s[hc * 8 + hh][kt * 8]);
          float4 wb = *reinterpret_cast<const float4*>(&fcw_s[hc * 8 + hh][kt * 8 + 4]);
          #pragma unroll
          for (int jj = 0; jj < 6; ++jj) {
            unsigned int u = reinterpret_cast<const unsigned int*>(&dv[jj])[hh >> 1];
            float d = (hh & 1) ? __uint_as_float(u & 0xffff0000u)
                               : __uint_as_float(u << 16);
            float a = d * xh[hh];
            acc[jj][0] = fmaf(a, wa.x, acc[jj][0]);
            acc[jj][1] = fmaf(a, wa.y, acc[jj][1]);
            acc[jj][2] = fmaf(a, wa.z, acc[jj][2]);
            acc[jj][3] = fmaf(a, wa.w, acc[jj][3]);
            acc[jj][4] = fmaf(a, wb.x, acc[jj][4]);
            acc[jj][5] = fmaf(a, wb.y, acc[jj][5]);
            acc[jj][6] = fmaf(a, wb.z, acc[jj][6]);
            acc[jj][7] = fmaf(a, wb.w, acc[jj][7]);
          }
        }
      }
      #pragma unroll
      for (int jj = 0; jj < 6; ++jj)
        #pragma unroll
        for (int kk = 0; kk < 8; ++kk)
          atomicAdd(&cx[0][j0 + jj][kt * 8 + kk], fast_tanh(acc[jj][kk]));
    }
    __syncthreads();
  }

  for (int t = tid; t < n * 16; t += NT) {
    int j = t >> 4, c = t & 15;
    if (c < 15) {
      float acc = 0.f;
      #pragma unroll
      for (int hc = 0; hc < 8; ++hc) {
        float4 c4 = *reinterpret_cast<const float4*>(&cx[0][j][hc * 4]);
        acc = fmaf(c4.x, w1_s[hc * 4 + 0][c], acc);
        acc = fmaf(c4.y, w1_s[hc * 4 + 1][c], acc);
        acc = fmaf(c4.z, w1_s[hc * 4 + 2][c], acc);
        acc = fmaf(c4.w, w1_s[hc * 4 + 3][c], acc);
      }
      atomicAdd(&bsum, fast_tanh(acc + b1_s[c]) * w2_s[c]);
    }
  }
  __syncthreads();
  if (tid == 0) outg[b] = bsum + (float)n * b2g[0];
}

extern "C" void kernel_launch(void* const* d_in, const int* in_sizes, int n_in,
                              void* d_out, int out_size, void* d_ws, size_t ws_size,
                              hipStream_t stream) {
  (void)in_sizes; (void)n_in;
  const int*   Z   = (const int*)d_in[0];
  const float* D   = (const float*)d_in[1];
  const int*   sz  = (const int*)d_in[2];
  const float* emb = (const float*)d_in[3];
  const float* dfw = (const float*)d_in[4];
  const float* dfb = (const float*)d_in[5];
  const float* cfw = (const float*)d_in[6];
  const float* cfb = (const float*)d_in[7];
  const float* fcw = (const float*)d_in[8];
  const float* w1  = (const float*)d_in[9];
  const float* b1  = (const float*)d_in[10];
  const float* w2  = (const float*)d_in[11];
  const float* b2  = (const float*)d_in[12];
  float* out = (float*)d_out;
  const int B = out_size;  // 2048

  const size_t need = (size_t)B * 3600 * sizeof(int4);  // 118 MB d_hat
  if (ws_size >= need && (B & 1) == 0) {
    mdtnn_phaseA<<<dim3(B), dim3(NT), 0, stream>>>(D, sz, dfw, dfb, (int4*)d_ws);
    mdtnn_phaseB<<<dim3(B / 2), dim3(NT), 0, stream>>>(Z, sz, emb, cfw, cfb, fcw,
                                                       w1, b1, w2, b2,
                                                       (const int4*)d_ws, out);
  } else {
    mdtnn_fused<<<dim3(B), dim3(NT), 0, stream>>>(Z, D, sz, emb, dfw, dfb, cfw, cfb,
                                                  fcw, w1, b1, w2, b2, out);
  }
}

// Round 4
// 482.994 us; speedup vs baseline: 1.8464x; 1.8464x over previous
//
#include <hip/hip_runtime.h>

#define NT 256

__device__ __forceinline__ float fast_tanh(float x) {
  float cl = fminf(fmaxf(x, -15.f), 15.f);
  float e = __builtin_amdgcn_exp2f(cl * 2.885390081777927f);  // exp(2x)
  return (e - 1.f) * __builtin_amdgcn_rcpf(e + 1.f);
}

__device__ __forceinline__ unsigned int pack2_bf16(float a, float b) {
  unsigned int ua = __float_as_uint(a);
  unsigned int ub = __float_as_uint(b);
  ua = (ua + 0x7fffu + ((ua >> 16) & 1u)) >> 16;
  ub = (ub + 0x7fffu + ((ub >> 16) & 1u)) & 0xffff0000u;
  return ua | ub;
}

// d_hat global layout (int4 units): [b][jj(6)][i(30)][jt(5)][ht(4)]
//   addr = b*3600 + jj*600 + (i*5 + jt)*4 + ht

// ---------------------------------------------------------------------------
// Kernel A: d_hat[i][j][h] = D[b,i,j,:] @ df_w + df_b  (bf16 to global)
// launch_bounds(NT,2): empirically gives 128 VGPRs (R1) -> no spills.
// ---------------------------------------------------------------------------
__global__ __launch_bounds__(NT, 2) void mdtnn_phaseA(
    const float* __restrict__ Dg, const int* __restrict__ sizesg,
    const float* __restrict__ dfwg, const float* __restrict__ dfbg,
    int4* __restrict__ dhg)
{
  const int b = blockIdx.x;
  const int tid = threadIdx.x;
  const int n = sizesg[b];
  const int njt = (n + 5) / 6;

  __shared__ __align__(16) float dfwT[32][56];
  __shared__ float dfb_s[32];

  for (int t = tid; t < 32 * 56; t += NT) {
    int h = t / 56, g = t - h * 56;
    dfwT[h][g] = (h < 30) ? dfwg[g * 30 + h] : 0.f;
  }
  if (tid < 32) dfb_s[tid] = (tid < 30) ? dfbg[tid] : 0.f;
  __syncthreads();

  const int tasks = n * njt * 4;       // (i, j-tile of 6, h-tile of 8)
  for (int task = tid; task < tasks; task += NT) {
    const int ht = task & 3;
    const int tmp = task >> 2;
    const int jt = tmp % njt;
    const int i = tmp / njt;
    const int j0 = jt * 6;
    const float* Dp = Dg + (((size_t)b * 30 + i) * 30 + j0) * 56;
    float acc[6][8];
    #pragma unroll
    for (int jj = 0; jj < 6; ++jj)
      #pragma unroll
      for (int hh = 0; hh < 8; ++hh) acc[jj][hh] = 0.f;

    #pragma unroll 2
    for (int gc = 0; gc < 14; ++gc) {
      float4 dj[6];
      #pragma unroll
      for (int jj = 0; jj < 6; ++jj)
        dj[jj] = *reinterpret_cast<const float4*>(Dp + jj * 56 + gc * 4);
      #pragma unroll
      for (int hh = 0; hh < 8; ++hh) {
        float4 w = *reinterpret_cast<const float4*>(&dfwT[ht * 8 + hh][gc * 4]);
        #pragma unroll
        for (int jj = 0; jj < 6; ++jj) {
          acc[jj][hh] = fmaf(dj[jj].x, w.x, acc[jj][hh]);
          acc[jj][hh] = fmaf(dj[jj].y, w.y, acc[jj][hh]);
          acc[jj][hh] = fmaf(dj[jj].z, w.z, acc[jj][hh]);
          acc[jj][hh] = fmaf(dj[jj].w, w.w, acc[jj][hh]);
        }
      }
    }
    int4* outp = dhg + (size_t)b * 3600 + (i * 5 + jt) * 4 + ht;
    #pragma unroll
    for (int jj = 0; jj < 6; ++jj) {
      int4 pk;
      pk.x = (int)pack2_bf16(acc[jj][0] + dfb_s[ht * 8 + 0], acc[jj][1] + dfb_s[ht * 8 + 1]);
      pk.y = (int)pack2_bf16(acc[jj][2] + dfb_s[ht * 8 + 2], acc[jj][3] + dfb_s[ht * 8 + 3]);
      pk.z = (int)pack2_bf16(acc[jj][4] + dfb_s[ht * 8 + 4], acc[jj][5] + dfb_s[ht * 8 + 5]);
      pk.w = (int)pack2_bf16(acc[jj][6] + dfb_s[ht * 8 + 6], acc[jj][7] + dfb_s[ht * 8 + 7]);
      outp[jj * 600] = pk;
    }
  }
}

// ---------------------------------------------------------------------------
// Kernel B: 3 iterations + head. 2 molecules/block (lanes 0-127 / 128-255).
// Accumulate phase: lane owns (j-tile, k-quarter, i-chunk); loops i privately
// with per-i tanh, ONE set of 24 LDS atomics at the end. ~85 VGPR demand.
// ---------------------------------------------------------------------------
__global__ __launch_bounds__(NT, 2) void mdtnn_phaseB(
    const int* __restrict__ Zg, const int* __restrict__ sizesg,
    const float* __restrict__ embg, const float* __restrict__ cfwg,
    const float* __restrict__ cfbg, const float* __restrict__ fcwg,
    const float* __restrict__ w1g, const float* __restrict__ b1g,
    const float* __restrict__ w2g, const float* __restrict__ b2g,
    const int4* __restrict__ dhg, float* __restrict__ outg)
{
  const int tid = threadIdx.x;
  const int m = tid >> 7;            // molecule slot 0/1
  const int lt = tid & 127;          // lane within slot
  const int b = blockIdx.x * 2 + m;
  const int n = sizesg[b];
  const int njt = (n + 5) / 6;

  __shared__ __align__(16) float cx[2][2][30][36];   // [mol][C/X1][row][cols]
  __shared__ __align__(16) float cfw_s[32][32];
  __shared__ __align__(16) float fcw_s[32][32];
  __shared__ __align__(16) float w1_s[32][16];
  __shared__ float cfb_s[32];
  __shared__ float b1_s[16];
  __shared__ float w2_s[16];
  __shared__ float wsum_s[2][2];

  for (int t = tid; t < 1024; t += NT) {
    int h = t >> 5, k = t & 31;
    bool in = (h < 30) && (k < 30);
    cfw_s[h][k] = in ? cfwg[h * 30 + k] : 0.f;
    fcw_s[h][k] = in ? fcwg[h * 30 + k] : 0.f;
  }
  for (int t = tid; t < 512; t += NT) {
    int h = t >> 4, c = t & 15;
    w1_s[h][c] = ((h < 30) && (c < 15)) ? w1g[h * 15 + c] : 0.f;
  }
  if (tid < 32) cfb_s[tid] = (tid < 30) ? cfbg[tid] : 0.f;
  if (tid < 16) {
    b1_s[tid] = (tid < 15) ? b1g[tid] : 0.f;
    w2_s[tid] = (tid < 15) ? w2g[tid] : 0.f;
  }

  // init C from embeddings
  for (int t = lt; t < n * 32; t += 128) {
    int i = t >> 5, h = t & 31;
    int z = Zg[b * 30 + i];
    cx[m][0][i][h] = (h < 30) ? embg[z * 30 + h] : 0.f;
  }
  __syncthreads();

  const int4* dhb = dhg + (size_t)b * 3600;

  // accumulate-phase lane decomposition (constant across iterations)
  const int P = njt * 8;             // (jt, kt) pairs; kt in [0,8) -> 4-wide k
  const int nch = 128 / P;           // i-chunks in flight (3..16)
  const int pk_ = lt % P;
  const int ch = lt / P;
  const int jt = pk_ >> 3, kt = pk_ & 7;
  const int j0 = jt * 6;
  const bool active = (ch < nch) && (ch < n);

  for (int it = 0; it < 3; ++it) {
    // X1 = C @ cf_w + cf_b
    for (int t = lt; t < n * 8; t += 128) {
      int i = t >> 3, kq = t & 7;
      float a0 = 0.f, a1 = 0.f, a2 = 0.f, a3 = 0.f;
      #pragma unroll
      for (int hc = 0; hc < 8; ++hc) {
        float4 c4 = *reinterpret_cast<const float4*>(&cx[m][0][i][hc * 4]);
        float cv[4] = {c4.x, c4.y, c4.z, c4.w};
        #pragma unroll
        for (int q = 0; q < 4; ++q) {
          float4 w = *reinterpret_cast<const float4*>(&cfw_s[hc * 4 + q][kq * 4]);
          a0 = fmaf(cv[q], w.x, a0);
          a1 = fmaf(cv[q], w.y, a1);
          a2 = fmaf(cv[q], w.z, a2);
          a3 = fmaf(cv[q], w.w, a3);
        }
      }
      float4 o = {a0 + cfb_s[kq * 4 + 0], a1 + cfb_s[kq * 4 + 1],
                  a2 + cfb_s[kq * 4 + 2], a3 + cfb_s[kq * 4 + 3]};
      *reinterpret_cast<float4*>(&cx[m][1][i][kq * 4]) = o;
    }
    __syncthreads();

    // C[j] += sum_i tanh( (X1[i] ⊙ dh[i][j]) @ fc_w )
    if (active) {
      float acc[6][4];
      #pragma unroll
      for (int jj = 0; jj < 6; ++jj)
        #pragma unroll
        for (int kk = 0; kk < 4; ++kk) acc[jj][kk] = 0.f;

      for (int i = ch; i < n; i += nch) {
        const int4* dhp = dhb + (i * 5 + jt) * 4;
        float g[6][4];
        #pragma unroll
        for (int jj = 0; jj < 6; ++jj)
          #pragma unroll
          for (int kk = 0; kk < 4; ++kk) g[jj][kk] = 0.f;

        #pragma unroll 2
        for (int hc = 0; hc < 4; ++hc) {
          int4 dv[6];
          #pragma unroll
          for (int jj = 0; jj < 6; ++jj)
            dv[jj] = dhp[jj * 600 + hc];
          float4 xa = *reinterpret_cast<const float4*>(&cx[m][1][i][hc * 8]);
          float4 xb = *reinterpret_cast<const float4*>(&cx[m][1][i][hc * 8 + 4]);
          float xh[8] = {xa.x, xa.y, xa.z, xa.w, xb.x, xb.y, xb.z, xb.w};
          #pragma unroll
          for (int hh = 0; hh < 8; ++hh) {
            float4 w = *reinterpret_cast<const float4*>(&fcw_s[hc * 8 + hh][kt * 4]);
            #pragma unroll
            for (int jj = 0; jj < 6; ++jj) {
              unsigned int u = reinterpret_cast<const unsigned int*>(&dv[jj])[hh >> 1];
              float d = (hh & 1) ? __uint_as_float(u & 0xffff0000u)
                                 : __uint_as_float(u << 16);
              float a = d * xh[hh];
              g[jj][0] = fmaf(a, w.x, g[jj][0]);
              g[jj][1] = fmaf(a, w.y, g[jj][1]);
              g[jj][2] = fmaf(a, w.z, g[jj][2]);
              g[jj][3] = fmaf(a, w.w, g[jj][3]);
            }
          }
        }
        #pragma unroll
        for (int jj = 0; jj < 6; ++jj)
          #pragma unroll
          for (int kk = 0; kk < 4; ++kk)
            acc[jj][kk] += fast_tanh(g[jj][kk]);
      }

      #pragma unroll
      for (int jj = 0; jj < 6; ++jj)
        #pragma unroll
        for (int kk = 0; kk < 4; ++kk)
          atomicAdd(&cx[m][0][j0 + jj][kt * 4 + kk], acc[jj][kk]);
    }
    __syncthreads();
  }

  // MLP head + masked reduce
  float e = 0.f;
  for (int t = lt; t < n * 16; t += 128) {
    int j = t >> 4, c = t & 15;
    if (c < 15) {
      float acc = 0.f;
      #pragma unroll
      for (int hc = 0; hc < 8; ++hc) {
        float4 c4 = *reinterpret_cast<const float4*>(&cx[m][0][j][hc * 4]);
        acc = fmaf(c4.x, w1_s[hc * 4 + 0][c], acc);
        acc = fmaf(c4.y, w1_s[hc * 4 + 1][c], acc);
        acc = fmaf(c4.z, w1_s[hc * 4 + 2][c], acc);
        acc = fmaf(c4.w, w1_s[hc * 4 + 3][c], acc);
      }
      e += fast_tanh(acc + b1_s[c]) * w2_s[c];
    }
  }
  #pragma unroll
  for (int off = 32; off; off >>= 1) e += __shfl_down(e, off);
  if ((tid & 63) == 0) wsum_s[m][(lt >> 6)] = e;
  __syncthreads();
  if (lt == 0) outg[b] = wsum_s[m][0] + wsum_s[m][1] + (float)n * b2g[0];
}

// ---------------------------------------------------------------------------
// Fallback (round-1 kernel, d_hat in LDS) for ws_size < 118 MB.
// ---------------------------------------------------------------------------
__global__ __launch_bounds__(NT, 2) void mdtnn_fused(
    const int* __restrict__ Zg, const float* __restrict__ Dg,
    const int* __restrict__ sizesg, const float* __restrict__ embg,
    const float* __restrict__ dfwg, const float* __restrict__ dfbg,
    const float* __restrict__ cfwg, const float* __restrict__ cfbg,
    const float* __restrict__ fcwg, const float* __restrict__ w1g,
    const float* __restrict__ b1g, const float* __restrict__ w2g,
    const float* __restrict__ b2g, float* __restrict__ outg)
{
  const int b = blockIdx.x;
  const int tid = threadIdx.x;
  const int n = sizesg[b];
  const int njt = (n + 5) / 6;

  __shared__ __align__(16) float cx[2][30][32];
  __shared__ __align__(16) float cfw_s[32][32];
  __shared__ __align__(16) float fcw_s[32][32];
  __shared__ __align__(16) float w1_s[32][16];
  __shared__ __align__(16) int4 dh2[30 * 121];
  __shared__ float dfb_s[32];
  __shared__ float cfb_s[32];
  __shared__ float b1_s[16];
  __shared__ float w2_s[16];
  __shared__ float bsum;

  float (*dfwT)[56] = reinterpret_cast<float (*)[56]>(&cx[0][0][0]);

  for (int t = tid; t < 32 * 56; t += NT) {
    int h = t / 56, g = t - h * 56;
    dfwT[h][g] = (h < 30) ? dfwg[g * 30 + h] : 0.f;
  }
  for (int t = tid; t < 1024; t += NT) {
    int h = t >> 5, k = t & 31;
    bool in = (h < 30) && (k < 30);
    cfw_s[h][k] = in ? cfwg[h * 30 + k] : 0.f;
    fcw_s[h][k] = in ? fcwg[h * 30 + k] : 0.f;
  }
  for (int t = tid; t < 512; t += NT) {
    int h = t >> 4, c = t & 15;
    w1_s[h][c] = ((h < 30) && (c < 15)) ? w1g[h * 15 + c] : 0.f;
  }
  if (tid < 32) {
    dfb_s[tid] = (tid < 30) ? dfbg[tid] : 0.f;
    cfb_s[tid] = (tid < 30) ? cfbg[tid] : 0.f;
  }
  if (tid < 16) {
    b1_s[tid] = (tid < 15) ? b1g[tid] : 0.f;
    w2_s[tid] = (tid < 15) ? w2g[tid] : 0.f;
  }
  if (tid == 0) bsum = 0.f;
  __syncthreads();

  {
    const int tasksA = n * njt * 4;
    for (int task = tid; task < tasksA; task += NT) {
      const int ht = task & 3;
      const int tmp = task >> 2;
      const int jt = tmp % njt;
      const int i = tmp / njt;
      const int j0 = jt * 6;
      const float* Dp = Dg + (((size_t)b * 30 + i) * 30 + j0) * 56;
      float acc[6][8];
      #pragma unroll
      for (int jj = 0; jj < 6; ++jj)
        #pragma unroll
        for (int hh = 0; hh < 8; ++hh) acc[jj][hh] = 0.f;
      #pragma unroll 2
      for (int gc = 0; gc < 14; ++gc) {
        float4 dj[6];
        #pragma unroll
        for (int jj = 0; jj < 6; ++jj)
          dj[jj] = *reinterpret_cast<const float4*>(Dp + jj * 56 + gc * 4);
        #pragma unroll
        for (int hh = 0; hh < 8; ++hh) {
          float4 w = *reinterpret_cast<const float4*>(&dfwT[ht * 8 + hh][gc * 4]);
          #pragma unroll
          for (int jj = 0; jj < 6; ++jj) {
            acc[jj][hh] = fmaf(dj[jj].x, w.x, acc[jj][hh]);
            acc[jj][hh] = fmaf(dj[jj].y, w.y, acc[jj][hh]);
            acc[jj][hh] = fmaf(dj[jj].z, w.z, acc[jj][hh]);
            acc[jj][hh] = fmaf(dj[jj].w, w.w, acc[jj][hh]);
          }
        }
      }
      #pragma unroll
      for (int jj = 0; jj < 6; ++jj) {
        int4 pk;
        pk.x = (int)pack2_bf16(acc[jj][0] + dfb_s[ht * 8 + 0], acc[jj][1] + dfb_s[ht * 8 + 1]);
        pk.y = (int)pack2_bf16(acc[jj][2] + dfb_s[ht * 8 + 2], acc[jj][3] + dfb_s[ht * 8 + 3]);
        pk.z = (int)pack2_bf16(acc[jj][4] + dfb_s[ht * 8 + 4], acc[jj][5] + dfb_s[ht * 8 + 5]);
        pk.w = (int)pack2_bf16(acc[jj][6] + dfb_s[ht * 8 + 6], acc[jj][7] + dfb_s[ht * 8 + 7]);
        dh2[i * 121 + ht * 30 + j0 + jj] = pk;
      }
    }
  }
  __syncthreads();

  for (int t = tid; t < n * 32; t += NT) {
    int i = t >> 5, h = t & 31;
    int z = Zg[b * 30 + i];
    cx[0][i][h] = (h < 30) ? embg[z * 30 + h] : 0.f;
  }
  __syncthreads();

  for (int it = 0; it < 3; ++it) {
    for (int task = tid; task < n * 4; task += NT) {
      int i = task >> 2, kt = task & 3;
      float acc[8];
      #pragma unroll
      for (int kk = 0; kk < 8; ++kk) acc[kk] = 0.f;
      #pragma unroll
      for (int hc = 0; hc < 8; ++hc) {
        float4 c4 = *reinterpret_cast<const float4*>(&cx[0][i][hc * 4]);
        float cv[4] = {c4.x, c4.y, c4.z, c4.w};
        #pragma unroll
        for (int q = 0; q < 4; ++q) {
          float4 wa = *reinterpret_cast<const float4*>(&cfw_s[hc * 4 + q][kt * 8]);
          float4 wb = *reinterpret_cast<const float4*>(&cfw_s[hc * 4 + q][kt * 8 + 4]);
          acc[0] = fmaf(cv[q], wa.x, acc[0]);
          acc[1] = fmaf(cv[q], wa.y, acc[1]);
          acc[2] = fmaf(cv[q], wa.z, acc[2]);
          acc[3] = fmaf(cv[q], wa.w, acc[3]);
          acc[4] = fmaf(cv[q], wb.x, acc[4]);
          acc[5] = fmaf(cv[q], wb.y, acc[5]);
          acc[6] = fmaf(cv[q], wb.z, acc[6]);
          acc[7] = fmaf(cv[q], wb.w, acc[7]);
        }
      }
      #pragma unroll
      for (int kk = 0; kk < 8; ++kk)
        cx[1][i][kt * 8 + kk] = acc[kk] + cfb_s[kt * 8 + kk];
    }
    __syncthreads();

    const int tasksB = n * njt * 4;
    for (int task = tid; task < tasksB; task += NT) {
      const int kt = task & 3;
      const int tmp = task >> 2;
      const int jt = tmp % njt;
      const int i = tmp / njt;
      const int j0 = jt * 6;
      float acc[6][8];
      #pragma unroll
      for (int jj = 0; jj < 6; ++jj)
        #pragma unroll
        for (int kk = 0; kk < 8; ++kk) acc[jj][kk] = 0.f;
      #pragma unroll 1
      for (int hc = 0; hc < 4; ++hc) {
        int4 dv[6];
        #pragma unroll
        for (int jj = 0; jj < 6; ++jj)
          dv[jj] = dh2[i * 121 + hc * 30 + j0 + jj];
        float4 xa = *reinterpret_cast<const float4*>(&cx[1][i][hc * 8]);
        float4 xb = *reinterpret_cast<const float4*>(&cx[1][i][hc * 8 + 4]);
        float xh[8] = {xa.x, xa.y, xa.z, xa.w, xb.x, xb.y, xb.z, xb.w};
        #pragma unroll
        for (int hh = 0; hh < 8; ++hh) {
          float4 wa = *reinterpret_cast<const float4*>(&fcw_s[hc * 8 + hh][kt * 8]);
          float4 wb = *reinterpret_cast<const float4*>(&fcw_s[hc * 8 + hh][kt * 8 + 4]);
          #pragma unroll
          for (int jj = 0; jj < 6; ++jj) {
            unsigned int u = reinterpret_cast<const unsigned int*>(&dv[jj])[hh >> 1];
            float d = (hh & 1) ? __uint_as_float(u & 0xffff0000u)
                               : __uint_as_float(u << 16);
            float a = d * xh[hh];
            acc[jj][0] = fmaf(a, wa.x, acc[jj][0]);
            acc[jj][1] = fmaf(a, wa.y, acc[jj][1]);
            acc[jj][2] = fmaf(a, wa.z, acc[jj][2]);
            acc[jj][3] = fmaf(a, wa.w, acc[jj][3]);
            acc[jj][4] = fmaf(a, wb.x, acc[jj][4]);
            acc[jj][5] = fmaf(a, wb.y, acc[jj][5]);
            acc[jj][6] = fmaf(a, wb.z, acc[jj][6]);
            acc[jj][7] = fmaf(a, wb.w, acc[jj][7]);
          }
        }
      }
      #pragma unroll
      for (int jj = 0; jj < 6; ++jj)
        #pragma unroll
        for (int kk = 0; kk < 8; ++kk)
          atomicAdd(&cx[0][j0 + jj][kt * 8 + kk], fast_tanh(acc[jj][kk]));
    }
    __syncthreads();
  }

  for (int t = tid; t < n * 16; t += NT) {
    int j = t >> 4, c = t & 15;
    if (c < 15) {
      float acc = 0.f;
      #pragma unroll
      for (int hc = 0; hc < 8; ++hc) {
        float4 c4 = *reinterpret_cast<const float4*>(&cx[0][j][hc * 4]);
        acc = fmaf(c4.x, w1_s[hc * 4 + 0][c], acc);
        acc = fmaf(c4.y, w1_s[hc * 4 + 1][c], acc);
        acc = fmaf(c4.z, w1_s[hc * 4 + 2][c], acc);
        acc = fmaf(c4.w, w1_s[hc * 4 + 3][c], acc);
      }
      atomicAdd(&bsum, fast_tanh(acc + b1_s[c]) * w2_s[c]);
    }
  }
  __syncthreads();
  if (tid == 0) outg[b] = bsum + (float)n * b2g[0];
}

extern "C" void kernel_launch(void* const* d_in, const int* in_sizes, int n_in,
                              void* d_out, int out_size, void* d_ws, size_t ws_size,
                              hipStream_t stream) {
  (void)in_sizes; (void)n_in;
  const int*   Z   = (const int*)d_in[0];
  const float* D   = (const float*)d_in[1];
  const int*   sz  = (const int*)d_in[2];
  const float* emb = (const float*)d_in[3];
  const float* dfw = (const float*)d_in[4];
  const float* dfb = (const float*)d_in[5];
  const float* cfw = (const float*)d_in[6];
  const float* cfb = (const float*)d_in[7];
  const float* fcw = (const float*)d_in[8];
  const float* w1  = (const float*)d_in[9];
  const float* b1  = (const float*)d_in[10];
  const float* w2  = (const float*)d_in[11];
  const float* b2  = (const float*)d_in[12];
  float* out = (float*)d_out;
  const int B = out_size;  // 2048

  const size_t need = (size_t)B * 3600 * sizeof(int4);  // 118 MB d_hat
  if (ws_size >= need && (B & 1) == 0) {
    mdtnn_phaseA<<<dim3(B), dim3(NT), 0, stream>>>(D, sz, dfw, dfb, (int4*)d_ws);
    mdtnn_phaseB<<<dim3(B / 2), dim3(NT), 0, stream>>>(Z, sz, emb, cfw, cfb, fcw,
                                                       w1, b1, w2, b2,
                                                       (const int4*)d_ws, out);
  } else {
    mdtnn_fused<<<dim3(B), dim3(NT), 0, stream>>>(Z, D, sz, emb, dfw, dfb, cfw, cfb,
                                                  fcw, w1, b1, w2, b2, out);
  }
}

// Round 6
// 217.962 us; speedup vs baseline: 4.0916x; 2.2160x over previous
//
#include <hip/hip_runtime.h>
#include <hip/hip_bf16.h>

typedef __attribute__((ext_vector_type(8))) short bh8;   // 8 x bf16 (4 VGPR) MFMA A/B frag
typedef __attribute__((ext_vector_type(4))) float f4;    // 4 x f32 MFMA C/D frag

#define MFMA_BF16 __builtin_amdgcn_mfma_f32_16x16x32_bf16

__device__ __forceinline__ float fast_tanh(float x) {
  float cl = fminf(fmaxf(x, -15.f), 15.f);
  float e = __builtin_amdgcn_exp2f(cl * 2.885390081777927f);  // exp(2x)
  return (e - 1.f) * __builtin_amdgcn_rcpf(e + 1.f);
}

// scalar cast -> compiler emits v_cvt_pk_bf16_f32 for pairs (m240)
__device__ __forceinline__ short bf16hi(float f, float* hf) {
  __hip_bfloat16 h = __float2bfloat16(f);
  *hf = __bfloat162float(h);
  short s;
  __builtin_memcpy(&s, &h, 2);
  return s;
}
__device__ __forceinline__ short bf16s(float f) {
  __hip_bfloat16 h = __float2bfloat16(f);
  short s;
  __builtin_memcpy(&s, &h, 2);
  return s;
}

__device__ __forceinline__ unsigned pack2_bf16(float a, float b) {
  unsigned ua = __float_as_uint(a);
  unsigned ub = __float_as_uint(b);
  ua = (ua + 0x7fffu + ((ua >> 16) & 1u)) >> 16;
  ub = (ub + 0x7fffu + ((ub >> 16) & 1u)) & 0xffff0000u;
  return ua | ub;
}

// d_hat layout: [b][i][j][h(32, bf16)] -> 64 B per (i,j) row, 4x uint4.

// ---------------------------------------------------------------------------
// Phase A: d_hat[i][j][h] = D[b,i,j,:] @ df_w + df_b (bf16, masked pairs only)
// ---------------------------------------------------------------------------
__global__ __launch_bounds__(256, 4) void mdtnn_phA(
    const float* __restrict__ Dg, const int* __restrict__ sizesg,
    const float* __restrict__ dfwg, const float* __restrict__ dfbg,
    uint4* __restrict__ dhg)
{
  const int b = blockIdx.x, tid = threadIdx.x;
  const int n = sizesg[b];

  __shared__ __align__(16) float dfw_s[56][32];
  __shared__ float dfb_s[32];
  for (int t = tid; t < 56 * 32; t += 256) {
    int g = t >> 5, h = t & 31;
    dfw_s[g][h] = (h < 30) ? dfwg[g * 30 + h] : 0.f;
  }
  if (tid < 32) dfb_s[tid] = (tid < 30) ? dfbg[tid] : 0.f;
  __syncthreads();

  const int nn = n * n;
  const float* Db = Dg + (size_t)b * (30 * 30 * 56);
  for (int p = tid; p < nn; p += 256) {
    const int i = p / n;
    const int j = p - i * n;
    const float* Dp = Db + (i * 30 + j) * 56;
    float acc[32];
    #pragma unroll
    for (int h = 0; h < 32; ++h) acc[h] = dfb_s[h];

    #pragma unroll 2
    for (int gc = 0; gc < 14; ++gc) {
      float4 d4 = *reinterpret_cast<const float4*>(Dp + gc * 4);
      #pragma unroll
      for (int gg = 0; gg < 4; ++gg) {
        const float dv = (&d4.x)[gg];
        #pragma unroll
        for (int hc = 0; hc < 8; ++hc) {
          float4 w = *reinterpret_cast<const float4*>(&dfw_s[gc * 4 + gg][hc * 4]);
          acc[hc * 4 + 0] = fmaf(dv, w.x, acc[hc * 4 + 0]);
          acc[hc * 4 + 1] = fmaf(dv, w.y, acc[hc * 4 + 1]);
          acc[hc * 4 + 2] = fmaf(dv, w.z, acc[hc * 4 + 2]);
          acc[hc * 4 + 3] = fmaf(dv, w.w, acc[hc * 4 + 3]);
        }
      }
    }
    uint4* outp = dhg + ((size_t)(b * 30 + i) * 30 + j) * 4;
    #pragma unroll
    for (int q = 0; q < 4; ++q) {
      uint4 pk;
      pk.x = pack2_bf16(acc[q * 8 + 0], acc[q * 8 + 1]);
      pk.y = pack2_bf16(acc[q * 8 + 2], acc[q * 8 + 3]);
      pk.z = pack2_bf16(acc[q * 8 + 4], acc[q * 8 + 5]);
      pk.w = pack2_bf16(acc[q * 8 + 6], acc[q * 8 + 7]);
      outp[q] = pk;  // acc[30],acc[31] exactly 0 (padded weights)
    }
  }
}

// ---------------------------------------------------------------------------
// Phase B: one molecule per 128-thread block (2 waves), MFMA 16x16x32 bf16.
//   X1 = (Ch+Cl) @ (cfwH+cfwL) + cfb          (6 MFMAs/wave, ~f32 accurate)
//   per i: W' = diag(X1[i]) * fc_w  (f32, split hi/lo)
//          g  = dh[i] @ (W'h + W'l)           (dh bits are the EXACT A frag)
//          C += tanh(g)  (register accum, one LDS-atomic commit per iter)
// Frag maps (m89-verified): A row=l&15, Kchunk=(l>>4)*8+e; B col=l&15, same K;
//                           D col=l&15, row=(l>>4)*4+e.
// ---------------------------------------------------------------------------
__global__ __launch_bounds__(128, 4) void mdtnn_phB(
    const int* __restrict__ Zg, const int* __restrict__ sizesg,
    const float* __restrict__ embg, const float* __restrict__ cfwg,
    const float* __restrict__ cfbg, const float* __restrict__ fcwg,
    const float* __restrict__ w1g, const float* __restrict__ b1g,
    const float* __restrict__ w2g, const float* __restrict__ b2g,
    const unsigned* __restrict__ dhg, float* __restrict__ outg)
{
  const int b = blockIdx.x, tid = threadIdx.x;
  const int wid = tid >> 6, l = tid & 63;
  const int lr = l & 15, lc = l >> 4;
  const int n = sizesg[b];

  __shared__ __align__(16) float C_lds[32][36];
  __shared__ __align__(16) float X1_lds[32][32];
  __shared__ __align__(16) float w1_s[32][16];
  __shared__ float b1_s[16], w2_s[16], wsum[2];

  for (int t = tid; t < 512; t += 128) {
    int k = t >> 4, c = t & 15;
    w1_s[k][c] = (k < 30 && c < 15) ? w1g[k * 15 + c] : 0.f;
  }
  if (tid < 16) {
    b1_s[tid] = (tid < 15) ? b1g[tid] : 0.f;
    w2_s[tid] = (tid < 15) ? w2g[tid] : 0.f;
  }
  for (int t = tid; t < 32 * 32; t += 128) {
    int j = t >> 5, k = t & 31;
    float v = 0.f;
    if (j < n && k < 30) v = embg[Zg[b * 30 + j] * 30 + k];
    C_lds[j][k] = v;
  }

  // f32 weight columns this lane needs (contraction index kk = lc*8+e)
  float fcwF0[8], fcwF1[8];
  bh8 cfwB0h, cfwB0l, cfwB1h, cfwB1l;
  #pragma unroll
  for (int e = 0; e < 8; ++e) {
    const int kk = lc * 8 + e;
    const int c1 = lr + 16;
    fcwF0[e] = (kk < 30) ? fcwg[kk * 30 + lr] : 0.f;
    fcwF1[e] = (kk < 30 && c1 < 30) ? fcwg[kk * 30 + c1] : 0.f;
    float g0 = (kk < 30) ? cfwg[kk * 30 + lr] : 0.f;
    float g1 = (kk < 30 && c1 < 30) ? cfwg[kk * 30 + c1] : 0.f;
    float hf;
    cfwB0h[e] = bf16hi(g0, &hf);
    cfwB0l[e] = bf16s(g0 - hf);
    cfwB1h[e] = bf16hi(g1, &hf);
    cfwB1l[e] = bf16s(g1 - hf);
  }
  const float cfb0 = cfbg[lr];                       // lr < 16 < 30
  const float cfb1 = (lr + 16 < 30) ? cfbg[lr + 16] : 0.f;

  const unsigned* dhb = dhg + (size_t)b * (30 * 30 * 16);  // dwords
  const f4 z4 = {0.f, 0.f, 0.f, 0.f};

  __syncthreads();

  for (int it = 0; it < 3; ++it) {
    // ---- X1 rows [wid*16, wid*16+16) = C @ cf_w + cf_b (split-precision) ----
    {
      const int row = wid * 16 + lr;
      float cv[8];
      *reinterpret_cast<float4*>(&cv[0]) =
          *reinterpret_cast<const float4*>(&C_lds[row][lc * 8]);
      *reinterpret_cast<float4*>(&cv[4]) =
          *reinterpret_cast<const float4*>(&C_lds[row][lc * 8 + 4]);
      bh8 Ch, Cl;
      #pragma unroll
      for (int e = 0; e < 8; ++e) {
        float hf;
        Ch[e] = bf16hi(cv[e], &hf);
        Cl[e] = bf16s(cv[e] - hf);
      }
      f4 d0 = MFMA_BF16(Ch, cfwB0l, z4, 0, 0, 0);
      d0 = MFMA_BF16(Cl, cfwB0h, d0, 0, 0, 0);
      d0 = MFMA_BF16(Ch, cfwB0h, d0, 0, 0, 0);
      f4 d1 = MFMA_BF16(Ch, cfwB1l, z4, 0, 0, 0);
      d1 = MFMA_BF16(Cl, cfwB1h, d1, 0, 0, 0);
      d1 = MFMA_BF16(Ch, cfwB1h, d1, 0, 0, 0);
      #pragma unroll
      for (int e = 0; e < 4; ++e) {
        int r = wid * 16 + lc * 4 + e;
        X1_lds[r][lr] = d0[e] + cfb0;
        X1_lds[r][lr + 16] = d1[e] + cfb1;
      }
    }
    __syncthreads();

    // ---- accumulate: wave handles i = wid, wid+2, ... ----
    f4 inc00 = z4, inc01 = z4, inc10 = z4, inc11 = z4;
    {
      const int j0 = lr, j1 = lr + 16;
      uint4 a0c = {0, 0, 0, 0}, a1c = {0, 0, 0, 0};
      if (wid < n) {
        const unsigned* p = dhb + (size_t)wid * 480;
        if (j0 < n) a0c = *reinterpret_cast<const uint4*>(p + j0 * 16 + lc * 4);
        if (j1 < n) a1c = *reinterpret_cast<const uint4*>(p + j1 * 16 + lc * 4);
      }
      for (int i = wid; i < n; i += 2) {
        uint4 a0n = {0, 0, 0, 0}, a1n = {0, 0, 0, 0};
        if (i + 2 < n) {
          const unsigned* p = dhb + (size_t)(i + 2) * 480;
          if (j0 < n) a0n = *reinterpret_cast<const uint4*>(p + j0 * 16 + lc * 4);
          if (j1 < n) a1n = *reinterpret_cast<const uint4*>(p + j1 * 16 + lc * 4);
        }
        // W' = diag(X1[i]) * fc_w, f32 -> hi/lo bf16 B-fragments
        float4 xA = *reinterpret_cast<const float4*>(&X1_lds[i][lc * 8]);
        float4 xB = *reinterpret_cast<const float4*>(&X1_lds[i][lc * 8 + 4]);
        float xv[8] = {xA.x, xA.y, xA.z, xA.w, xB.x, xB.y, xB.z, xB.w};
        bh8 W0h, W0l, W1h, W1l;
        #pragma unroll
        for (int e = 0; e < 8; ++e) {
          float p0 = xv[e] * fcwF0[e];
          float p1 = xv[e] * fcwF1[e];
          float hf;
          W0h[e] = bf16hi(p0, &hf);
          W0l[e] = bf16s(p0 - hf);
          W1h[e] = bf16hi(p1, &hf);
          W1l[e] = bf16s(p1 - hf);
        }
        const bh8 A0 = *reinterpret_cast<const bh8*>(&a0c);
        const bh8 A1 = *reinterpret_cast<const bh8*>(&a1c);
        f4 g;
        g = MFMA_BF16(A0, W0l, z4, 0, 0, 0);
        g = MFMA_BF16(A0, W0h, g, 0, 0, 0);
        #pragma unroll
        for (int e = 0; e < 4; ++e) inc00[e] += fast_tanh(g[e]);
        g = MFMA_BF16(A0, W1l, z4, 0, 0, 0);
        g = MFMA_BF16(A0, W1h, g, 0, 0, 0);
        #pragma unroll
        for (int e = 0; e < 4; ++e) inc01[e] += fast_tanh(g[e]);
        g = MFMA_BF16(A1, W0l, z4, 0, 0, 0);
        g = MFMA_BF16(A1, W0h, g, 0, 0, 0);
        #pragma unroll
        for (int e = 0; e < 4; ++e) inc10[e] += fast_tanh(g[e]);
        g = MFMA_BF16(A1, W1l, z4, 0, 0, 0);
        g = MFMA_BF16(A1, W1h, g, 0, 0, 0);
        #pragma unroll
        for (int e = 0; e < 4; ++e) inc11[e] += fast_tanh(g[e]);
        a0c = a0n;
        a1c = a1n;
      }
    }
    #pragma unroll
    for (int e = 0; e < 4; ++e) {
      atomicAdd(&C_lds[lc * 4 + e][lr], inc00[e]);
      atomicAdd(&C_lds[lc * 4 + e][lr + 16], inc01[e]);
      atomicAdd(&C_lds[16 + lc * 4 + e][lr], inc10[e]);
      atomicAdd(&C_lds[16 + lc * 4 + e][lr + 16], inc11[e]);
    }
    __syncthreads();
  }

  // ---- MLP head + masked reduce ----
  float esum = 0.f;
  for (int t = tid; t < n * 16; t += 128) {
    int j = t >> 4, c = t & 15;
    if (c < 15) {
      float a = b1_s[c];
      #pragma unroll
      for (int kc = 0; kc < 8; ++kc) {
        float4 c4 = *reinterpret_cast<const float4*>(&C_lds[j][kc * 4]);
        a = fmaf(c4.x, w1_s[kc * 4 + 0][c], a);
        a = fmaf(c4.y, w1_s[kc * 4 + 1][c], a);
        a = fmaf(c4.z, w1_s[kc * 4 + 2][c], a);
        a = fmaf(c4.w, w1_s[kc * 4 + 3][c], a);
      }
      esum += fast_tanh(a) * w2_s[c];
    }
  }
  #pragma unroll
  for (int off = 32; off; off >>= 1) esum += __shfl_down(esum, off);
  if (l == 0) wsum[wid] = esum;
  __syncthreads();
  if (tid == 0) outg[b] = wsum[0] + wsum[1] + (float)n * b2g[0];
}

// ---------------------------------------------------------------------------
// Fallback (round-1 fused kernel, d_hat in LDS) for ws_size too small.
// ---------------------------------------------------------------------------
__global__ __launch_bounds__(256, 2) void mdtnn_fused(
    const int* __restrict__ Zg, const float* __restrict__ Dg,
    const int* __restrict__ sizesg, const float* __restrict__ embg,
    const float* __restrict__ dfwg, const float* __restrict__ dfbg,
    const float* __restrict__ cfwg, const float* __restrict__ cfbg,
    const float* __restrict__ fcwg, const float* __restrict__ w1g,
    const float* __restrict__ b1g, const float* __restrict__ w2g,
    const float* __restrict__ b2g, float* __restrict__ outg)
{
  const int b = blockIdx.x;
  const int tid = threadIdx.x;
  const int n = sizesg[b];
  const int njt = (n + 5) / 6;

  __shared__ __align__(16) float cx[2][30][32];
  __shared__ __align__(16) float cfw_s[32][32];
  __shared__ __align__(16) float fcw_s[32][32];
  __shared__ __align__(16) float w1_s[32][16];
  __shared__ __align__(16) int4 dh2[30 * 121];
  __shared__ float dfb_s[32];
  __shared__ float cfb_s[32];
  __shared__ float b1_s[16];
  __shared__ float w2_s[16];
  __shared__ float bsum;

  float (*dfwT)[56] = reinterpret_cast<float (*)[56]>(&cx[0][0][0]);

  for (int t = tid; t < 32 * 56; t += 256) {
    int h = t / 56, g = t - h * 56;
    dfwT[h][g] = (h < 30) ? dfwg[g * 30 + h] : 0.f;
  }
  for (int t = tid; t < 1024; t += 256) {
    int h = t >> 5, k = t & 31;
    bool in = (h < 30) && (k < 30);
    cfw_s[h][k] = in ? cfwg[h * 30 + k] : 0.f;
    fcw_s[h][k] = in ? fcwg[h * 30 + k] : 0.f;
  }
  for (int t = tid; t < 512; t += 256) {
    int h = t >> 4, c = t & 15;
    w1_s[h][c] = ((h < 30) && (c < 15)) ? w1g[h * 15 + c] : 0.f;
  }
  if (tid < 32) {
    dfb_s[tid] = (tid < 30) ? dfbg[tid] : 0.f;
    cfb_s[tid] = (tid < 30) ? cfbg[tid] : 0.f;
  }
  if (tid < 16) {
    b1_s[tid] = (tid < 15) ? b1g[tid] : 0.f;
    w2_s[tid] = (tid < 15) ? w2g[tid] : 0.f;
  }
  if (tid == 0) bsum = 0.f;
  __syncthreads();

  {
    const int tasksA = n * njt * 4;
    for (int task = tid; task < tasksA; task += 256) {
      const int ht = task & 3;
      const int tmp = task >> 2;
      const int jt = tmp % njt;
      const int i = tmp / njt;
      const int j0 = jt * 6;
      const float* Dp = Dg + (((size_t)b * 30 + i) * 30 + j0) * 56;
      float acc[6][8];
      #pragma unroll
      for (int jj = 0; jj < 6; ++jj)
        #pragma unroll
        for (int hh = 0; hh < 8; ++hh) acc[jj][hh] = 0.f;
      #pragma unroll 2
      for (int gc = 0; gc < 14; ++gc) {
        float4 dj[6];
        #pragma unroll
        for (int jj = 0; jj < 6; ++jj)
          dj[jj] = *reinterpret_cast<const float4*>(Dp + jj * 56 + gc * 4);
        #pragma unroll
        for (int hh = 0; hh < 8; ++hh) {
          float4 w = *reinterpret_cast<const float4*>(&dfwT[ht * 8 + hh][gc * 4]);
          #pragma unroll
          for (int jj = 0; jj < 6; ++jj) {
            acc[jj][hh] = fmaf(dj[jj].x, w.x, acc[jj][hh]);
            acc[jj][hh] = fmaf(dj[jj].y, w.y, acc[jj][hh]);
            acc[jj][hh] = fmaf(dj[jj].z, w.z, acc[jj][hh]);
            acc[jj][hh] = fmaf(dj[jj].w, w.w, acc[jj][hh]);
          }
        }
      }
      #pragma unroll
      for (int jj = 0; jj < 6; ++jj) {
        int4 pk;
        pk.x = (int)pack2_bf16(acc[jj][0] + dfb_s[ht * 8 + 0], acc[jj][1] + dfb_s[ht * 8 + 1]);
        pk.y = (int)pack2_bf16(acc[jj][2] + dfb_s[ht * 8 + 2], acc[jj][3] + dfb_s[ht * 8 + 3]);
        pk.z = (int)pack2_bf16(acc[jj][4] + dfb_s[ht * 8 + 4], acc[jj][5] + dfb_s[ht * 8 + 5]);
        pk.w = (int)pack2_bf16(acc[jj][6] + dfb_s[ht * 8 + 6], acc[jj][7] + dfb_s[ht * 8 + 7]);
        dh2[i * 121 + ht * 30 + j0 + jj] = pk;
      }
    }
  }
  __syncthreads();

  for (int t = tid; t < n * 32; t += 256) {
    int i = t >> 5, h = t & 31;
    int z = Zg[b * 30 + i];
    cx[0][i][h] = (h < 30) ? embg[z * 30 + h] : 0.f;
  }
  __syncthreads();

  for (int it = 0; it < 3; ++it) {
    for (int task = tid; task < n * 4; task += 256) {
      int i = task >> 2, kt = task & 3;
      float acc[8];
      #pragma unroll
      for (int kk = 0; kk < 8; ++kk) acc[kk] = 0.f;
      #pragma unroll
      for (int hc = 0; hc < 8; ++hc) {
        float4 c4 = *reinterpret_cast<const float4*>(&cx[0][i][hc * 4]);
        float cv[4] = {c4.x, c4.y, c4.z, c4.w};
        #pragma unroll
        for (int q = 0; q < 4; ++q) {
          float4 wa = *reinterpret_cast<const float4*>(&cfw_s[hc * 4 + q][kt * 8]);
          float4 wb = *reinterpret_cast<const float4*>(&cfw_s[hc * 4 + q][kt * 8 + 4]);
          acc[0] = fmaf(cv[q], wa.x, acc[0]);
          acc[1] = fmaf(cv[q], wa.y, acc[1]);
          acc[2] = fmaf(cv[q], wa.z, acc[2]);
          acc[3] = fmaf(cv[q], wa.w, acc[3]);
          acc[4] = fmaf(cv[q], wb.x, acc[4]);
          acc[5] = fmaf(cv[q], wb.y, acc[5]);
          acc[6] = fmaf(cv[q], wb.z, acc[6]);
          acc[7] = fmaf(cv[q], wb.w, acc[7]);
        }
      }
      #pragma unroll
      for (int kk = 0; kk < 8; ++kk)
        cx[1][i][kt * 8 + kk] = acc[kk] + cfb_s[kt * 8 + kk];
    }
    __syncthreads();

    const int tasksB = n * njt * 4;
    for (int task = tid; task < tasksB; task += 256) {
      const int kt = task & 3;
      const int tmp = task >> 2;
      const int jt = tmp % njt;
      const int i = tmp / njt;
      const int j0 = jt * 6;
      float acc[6][8];
      #pragma unroll
      for (int jj = 0; jj < 6; ++jj)
        #pragma unroll
        for (int kk = 0; kk < 8; ++kk) acc[jj][kk] = 0.f;
      #pragma unroll 1
      for (int hc = 0; hc < 4; ++hc) {
        int4 dv[6];
        #pragma unroll
        for (int jj = 0; jj < 6; ++jj)
          dv[jj] = dh2[i * 121 + hc * 30 + j0 + jj];
        float4 xa = *reinterpret_cast<const float4*>(&cx[1][i][hc * 8]);
        float4 xb = *reinterpret_cast<const float4*>(&cx[1][i][hc * 8 + 4]);
        float xh[8] = {xa.x, xa.y, xa.z, xa.w, xb.x, xb.y, xb.z, xb.w};
        #pragma unroll
        for (int hh = 0; hh < 8; ++hh) {
          float4 wa = *reinterpret_cast<const float4*>(&fcw_s[hc * 8 + hh][kt * 8]);
          float4 wb = *reinterpret_cast<const float4*>(&fcw_s[hc * 8 + hh][kt * 8 + 4]);
          #pragma unroll
          for (int jj = 0; jj < 6; ++jj) {
            unsigned u = reinterpret_cast<const unsigned*>(&dv[jj])[hh >> 1];
            float d = (hh & 1) ? __uint_as_float(u & 0xffff0000u)
                               : __uint_as_float(u << 16);
            float a = d * xh[hh];
            acc[jj][0] = fmaf(a, wa.x, acc[jj][0]);
            acc[jj][1] = fmaf(a, wa.y, acc[jj][1]);
            acc[jj][2] = fmaf(a, wa.z, acc[jj][2]);
            acc[jj][3] = fmaf(a, wa.w, acc[jj][3]);
            acc[jj][4] = fmaf(a, wb.x, acc[jj][4]);
            acc[jj][5] = fmaf(a, wb.y, acc[jj][5]);
            acc[jj][6] = fmaf(a, wb.z, acc[jj][6]);
            acc[jj][7] = fmaf(a, wb.w, acc[jj][7]);
          }
        }
      }
      #pragma unroll
      for (int jj = 0; jj < 6; ++jj)
        #pragma unroll
        for (int kk = 0; kk < 8; ++kk)
          atomicAdd(&cx[0][j0 + jj][kt * 8 + kk], fast_tanh(acc[jj][kk]));
    }
    __syncthreads();
  }

  for (int t = tid; t < n * 16; t += 256) {
    int j = t >> 4, c = t & 15;
    if (c < 15) {
      float acc = 0.f;
      #pragma unroll
      for (int hc = 0; hc < 8; ++hc) {
        float4 c4 = *reinterpret_cast<const float4*>(&cx[0][j][hc * 4]);
        acc = fmaf(c4.x, w1_s[hc * 4 + 0][c], acc);
        acc = fmaf(c4.y, w1_s[hc * 4 + 1][c], acc);
        acc = fmaf(c4.z, w1_s[hc * 4 + 2][c], acc);
        acc = fmaf(c4.w, w1_s[hc * 4 + 3][c], acc);
      }
      atomicAdd(&bsum, fast_tanh(acc + b1_s[c]) * w2_s[c]);
    }
  }
  __syncthreads();
  if (tid == 0) outg[b] = bsum + (float)n * b2g[0];
}

extern "C" void kernel_launch(void* const* d_in, const int* in_sizes, int n_in,
                              void* d_out, int out_size, void* d_ws, size_t ws_size,
                              hipStream_t stream) {
  (void)in_sizes; (void)n_in;
  const int*   Z   = (const int*)d_in[0];
  const float* D   = (const float*)d_in[1];
  const int*   sz  = (const int*)d_in[2];
  const float* emb = (const float*)d_in[3];
  const float* dfw = (const float*)d_in[4];
  const float* dfb = (const float*)d_in[5];
  const float* cfw = (const float*)d_in[6];
  const float* cfb = (const float*)d_in[7];
  const float* fcw = (const float*)d_in[8];
  const float* w1  = (const float*)d_in[9];
  const float* b1  = (const float*)d_in[10];
  const float* w2  = (const float*)d_in[11];
  const float* b2  = (const float*)d_in[12];
  float* out = (float*)d_out;
  const int B = out_size;  // 2048

  const size_t need = (size_t)B * 30 * 30 * 64;  // 118 MB d_hat [b][i][j][h32] bf16
  if (ws_size >= need) {
    mdtnn_phA<<<dim3(B), dim3(256), 0, stream>>>(D, sz, dfw, dfb, (uint4*)d_ws);
    mdtnn_phB<<<dim3(B), dim3(128), 0, stream>>>(Z, sz, emb, cfw, cfb, fcw,
                                                 w1, b1, w2, b2,
                                                 (const unsigned*)d_ws, out);
  } else {
    mdtnn_fused<<<dim3(B), dim3(256), 0, stream>>>(Z, D, sz, emb, dfw, dfb, cfw, cfb,
                                                   fcw, w1, b1, w2, b2, out);
  }
}

// Round 7
// 154.673 us; speedup vs baseline: 5.7658x; 1.4092x over previous
//
#include <hip/hip_runtime.h>
#include <hip/hip_bf16.h>

typedef __attribute__((ext_vector_type(8))) short bh8;   // 8 x bf16 (4 VGPR) MFMA A/B frag
typedef __attribute__((ext_vector_type(4))) float f4;    // 4 x f32 MFMA C/D frag

#define MFMA_BF16 __builtin_amdgcn_mfma_f32_16x16x32_bf16

__device__ __forceinline__ float fast_tanh(float x) {
  float cl = fminf(fmaxf(x, -15.f), 15.f);
  float e = __builtin_amdgcn_exp2f(cl * 2.885390081777927f);  // exp(2x)
  return (e - 1.f) * __builtin_amdgcn_rcpf(e + 1.f);
}

// scalar cast -> compiler emits v_cvt_pk_bf16_f32 for pairs (m240)
__device__ __forceinline__ short bf16hi(float f, float* hf) {
  __hip_bfloat16 h = __float2bfloat16(f);
  *hf = __bfloat162float(h);
  short s;
  __builtin_memcpy(&s, &h, 2);
  return s;
}
__device__ __forceinline__ short bf16s(float f) {
  __hip_bfloat16 h = __float2bfloat16(f);
  short s;
  __builtin_memcpy(&s, &h, 2);
  return s;
}

__device__ __forceinline__ unsigned pack2_bf16(float a, float b) {
  unsigned ua = __float_as_uint(a);
  unsigned ub = __float_as_uint(b);
  ua = (ua + 0x7fffu + ((ua >> 16) & 1u)) >> 16;
  ub = (ub + 0x7fffu + ((ub >> 16) & 1u)) & 0xffff0000u;
  return ua | ub;
}

// d_hat layout: [b][i(30)][j(30)][h(32, bf16)] -> 64 B per (i,j) pair.

// ---------------------------------------------------------------------------
// Phase A (MFMA): d_hat[p=(i,j)][h] = D[b,i,j,:] @ df_w + df_b.
// GEMM per 16-pair tile: D-tile rows = h (A = dfw^T, hi/lo split, built once),
// cols = pairs (B = D rows as bf16). 8 MFMAs + ~45 VALU per tile vs 28.7k
// scalar FMAs. No LDS. Masked pairs only (flat p < n*n, magic-div for i,j).
// ---------------------------------------------------------------------------
__global__ __launch_bounds__(256, 4) void mdtnn_phA_mfma(
    const float* __restrict__ Dg, const int* __restrict__ sizesg,
    const float* __restrict__ dfwg, const float* __restrict__ dfbg,
    uint2* __restrict__ dhg)
{
  const int b = blockIdx.x, tid = threadIdx.x;
  const int w = tid >> 6, l = tid & 63;
  const int lr = l & 15, lc = l >> 4;
  const int n = sizesg[b];
  const int nn = n * n;
  const unsigned inv = (65536u + (unsigned)n - 1) / (unsigned)n;  // exact p/n for p<1024

  // A fragments: dfw^T (row=h=lr(+16), K=g=lc*8+e), hi/lo split, zero-padded.
  bh8 Ah[2][2], Al[2][2];
  #pragma unroll
  for (int ht = 0; ht < 2; ++ht) {
    const int h = ht * 16 + lr;
    #pragma unroll
    for (int kc = 0; kc < 2; ++kc) {
      #pragma unroll
      for (int e = 0; e < 8; ++e) {
        const int g = kc * 32 + lc * 8 + e;
        float v = (g < 56 && h < 30) ? dfwg[g * 30 + h] : 0.f;
        float hf;
        Ah[ht][kc][e] = bf16hi(v, &hf);
        Al[ht][kc][e] = bf16s(v - hf);
      }
    }
  }
  // dfb for the 8 h-rows this lane produces (D-frag row = lc*4+e)
  float dfbv[2][4];
  #pragma unroll
  for (int ht = 0; ht < 2; ++ht)
    #pragma unroll
    for (int e = 0; e < 4; ++e) {
      const int h = ht * 16 + lc * 4 + e;
      dfbv[ht][e] = (h < 30) ? dfbg[h] : 0.f;
    }

  const float* Db = Dg + (size_t)b * (30 * 30 * 56);
  uint2* dhb = dhg + (size_t)b * (30 * 30 * 8);
  const f4 z4 = {0.f, 0.f, 0.f, 0.f};

  const int tiles = (nn + 15) >> 4;
  for (int t = w; t < tiles; t += 4) {
    const int p_raw = t * 16 + lr;             // this lane's pair (B/D col)
    const int p = min(p_raw, nn - 1);
    const int i = (int)(((unsigned)p * inv) >> 16);
    const int j = p - i * n;
    const int row = i * 30 + j;                // storage pair index
    const float* Dp = Db + (size_t)row * 56;

    // B fragments: K-chunk0 g=[lc*8, lc*8+8), chunk1 g=[32+lc*8, ...) (lc<3)
    float4 q0 = *reinterpret_cast<const float4*>(Dp + lc * 8);
    float4 q1 = *reinterpret_cast<const float4*>(Dp + lc * 8 + 4);
    float4 q2 = {0.f, 0.f, 0.f, 0.f}, q3 = {0.f, 0.f, 0.f, 0.f};
    if (lc < 3) {  // g >= 56 rows of A are zero; avoids OOB read on last pair
      q2 = *reinterpret_cast<const float4*>(Dp + 32 + lc * 8);
      q3 = *reinterpret_cast<const float4*>(Dp + 32 + lc * 8 + 4);
    }
    bh8 B0, B1;
    B0[0] = bf16s(q0.x); B0[1] = bf16s(q0.y); B0[2] = bf16s(q0.z); B0[3] = bf16s(q0.w);
    B0[4] = bf16s(q1.x); B0[5] = bf16s(q1.y); B0[6] = bf16s(q1.z); B0[7] = bf16s(q1.w);
    B1[0] = bf16s(q2.x); B1[1] = bf16s(q2.y); B1[2] = bf16s(q2.z); B1[3] = bf16s(q2.w);
    B1[4] = bf16s(q3.x); B1[5] = bf16s(q3.y); B1[6] = bf16s(q3.z); B1[7] = bf16s(q3.w);

    f4 a0 = z4, a1 = z4;
    a0 = MFMA_BF16(Al[0][0], B0, a0, 0, 0, 0);
    a0 = MFMA_BF16(Ah[0][0], B0, a0, 0, 0, 0);
    a0 = MFMA_BF16(Al[0][1], B1, a0, 0, 0, 0);
    a0 = MFMA_BF16(Ah[0][1], B1, a0, 0, 0, 0);
    a1 = MFMA_BF16(Al[1][0], B0, a1, 0, 0, 0);
    a1 = MFMA_BF16(Ah[1][0], B0, a1, 0, 0, 0);
    a1 = MFMA_BF16(Al[1][1], B1, a1, 0, 0, 0);
    a1 = MFMA_BF16(Ah[1][1], B1, a1, 0, 0, 0);

    if (p_raw < nn) {
      uint2 s0, s1;
      s0.x = pack2_bf16(a0[0] + dfbv[0][0], a0[1] + dfbv[0][1]);
      s0.y = pack2_bf16(a0[2] + dfbv[0][2], a0[3] + dfbv[0][3]);
      s1.x = pack2_bf16(a1[0] + dfbv[1][0], a1[1] + dfbv[1][1]);
      s1.y = pack2_bf16(a1[2] + dfbv[1][2], a1[3] + dfbv[1][3]);
      dhb[row * 8 + 0 * 4 + lc] = s0;   // h = 0*16 + lc*4 .. +3
      dhb[row * 8 + 1 * 4 + lc] = s1;   // h = 16   + lc*4 .. +3
    }
  }
}

// ---------------------------------------------------------------------------
// Phase B (unchanged from R6): one molecule per 128-thread block (2 waves).
//   X1 = (Ch+Cl) @ (cfwH+cfwL) + cfb          (6 MFMAs/wave)
//   per i: W' = diag(X1[i]) * fc_w (f32, hi/lo split); g = dh[i] @ (W'h+W'l)
//          C += tanh(g)  (register accum, one LDS-atomic commit per iter)
// ---------------------------------------------------------------------------
__global__ __launch_bounds__(128, 4) void mdtnn_phB(
    const int* __restrict__ Zg, const int* __restrict__ sizesg,
    const float* __restrict__ embg, const float* __restrict__ cfwg,
    const float* __restrict__ cfbg, const float* __restrict__ fcwg,
    const float* __restrict__ w1g, const float* __restrict__ b1g,
    const float* __restrict__ w2g, const float* __restrict__ b2g,
    const unsigned* __restrict__ dhg, float* __restrict__ outg)
{
  const int b = blockIdx.x, tid = threadIdx.x;
  const int wid = tid >> 6, l = tid & 63;
  const int lr = l & 15, lc = l >> 4;
  const int n = sizesg[b];

  __shared__ __align__(16) float C_lds[32][36];
  __shared__ __align__(16) float X1_lds[32][32];
  __shared__ __align__(16) float w1_s[32][16];
  __shared__ float b1_s[16], w2_s[16], wsum[2];

  for (int t = tid; t < 512; t += 128) {
    int k = t >> 4, c = t & 15;
    w1_s[k][c] = (k < 30 && c < 15) ? w1g[k * 15 + c] : 0.f;
  }
  if (tid < 16) {
    b1_s[tid] = (tid < 15) ? b1g[tid] : 0.f;
    w2_s[tid] = (tid < 15) ? w2g[tid] : 0.f;
  }
  for (int t = tid; t < 32 * 32; t += 128) {
    int j = t >> 5, k = t & 31;
    float v = 0.f;
    if (j < n && k < 30) v = embg[Zg[b * 30 + j] * 30 + k];
    C_lds[j][k] = v;
  }

  float fcwF0[8], fcwF1[8];
  bh8 cfwB0h, cfwB0l, cfwB1h, cfwB1l;
  #pragma unroll
  for (int e = 0; e < 8; ++e) {
    const int kk = lc * 8 + e;
    const int c1 = lr + 16;
    fcwF0[e] = (kk < 30) ? fcwg[kk * 30 + lr] : 0.f;
    fcwF1[e] = (kk < 30 && c1 < 30) ? fcwg[kk * 30 + c1] : 0.f;
    float g0 = (kk < 30) ? cfwg[kk * 30 + lr] : 0.f;
    float g1 = (kk < 30 && c1 < 30) ? cfwg[kk * 30 + c1] : 0.f;
    float hf;
    cfwB0h[e] = bf16hi(g0, &hf);
    cfwB0l[e] = bf16s(g0 - hf);
    cfwB1h[e] = bf16hi(g1, &hf);
    cfwB1l[e] = bf16s(g1 - hf);
  }
  const float cfb0 = cfbg[lr];
  const float cfb1 = (lr + 16 < 30) ? cfbg[lr + 16] : 0.f;

  const unsigned* dhb = dhg + (size_t)b * (30 * 30 * 16);  // dwords
  const f4 z4 = {0.f, 0.f, 0.f, 0.f};

  __syncthreads();

  for (int it = 0; it < 3; ++it) {
    {
      const int row = wid * 16 + lr;
      float cv[8];
      *reinterpret_cast<float4*>(&cv[0]) =
          *reinterpret_cast<const float4*>(&C_lds[row][lc * 8]);
      *reinterpret_cast<float4*>(&cv[4]) =
          *reinterpret_cast<const float4*>(&C_lds[row][lc * 8 + 4]);
      bh8 Ch, Cl;
      #pragma unroll
      for (int e = 0; e < 8; ++e) {
        float hf;
        Ch[e] = bf16hi(cv[e], &hf);
        Cl[e] = bf16s(cv[e] - hf);
      }
      f4 d0 = MFMA_BF16(Ch, cfwB0l, z4, 0, 0, 0);
      d0 = MFMA_BF16(Cl, cfwB0h, d0, 0, 0, 0);
      d0 = MFMA_BF16(Ch, cfwB0h, d0, 0, 0, 0);
      f4 d1 = MFMA_BF16(Ch, cfwB1l, z4, 0, 0, 0);
      d1 = MFMA_BF16(Cl, cfwB1h, d1, 0, 0, 0);
      d1 = MFMA_BF16(Ch, cfwB1h, d1, 0, 0, 0);
      #pragma unroll
      for (int e = 0; e < 4; ++e) {
        int r = wid * 16 + lc * 4 + e;
        X1_lds[r][lr] = d0[e] + cfb0;
        X1_lds[r][lr + 16] = d1[e] + cfb1;
      }
    }
    __syncthreads();

    f4 inc00 = z4, inc01 = z4, inc10 = z4, inc11 = z4;
    {
      const int j0 = lr, j1 = lr + 16;
      uint4 a0c = {0, 0, 0, 0}, a1c = {0, 0, 0, 0};
      if (wid < n) {
        const unsigned* p = dhb + (size_t)wid * 480;
        if (j0 < n) a0c = *reinterpret_cast<const uint4*>(p + j0 * 16 + lc * 4);
        if (j1 < n) a1c = *reinterpret_cast<const uint4*>(p + j1 * 16 + lc * 4);
      }
      for (int i = wid; i < n; i += 2) {
        uint4 a0n = {0, 0, 0, 0}, a1n = {0, 0, 0, 0};
        if (i + 2 < n) {
          const unsigned* p = dhb + (size_t)(i + 2) * 480;
          if (j0 < n) a0n = *reinterpret_cast<const uint4*>(p + j0 * 16 + lc * 4);
          if (j1 < n) a1n = *reinterpret_cast<const uint4*>(p + j1 * 16 + lc * 4);
        }
        float4 xA = *reinterpret_cast<const float4*>(&X1_lds[i][lc * 8]);
        float4 xB = *reinterpret_cast<const float4*>(&X1_lds[i][lc * 8 + 4]);
        float xv[8] = {xA.x, xA.y, xA.z, xA.w, xB.x, xB.y, xB.z, xB.w};
        bh8 W0h, W0l, W1h, W1l;
        #pragma unroll
        for (int e = 0; e < 8; ++e) {
          float p0 = xv[e] * fcwF0[e];
          float p1 = xv[e] * fcwF1[e];
          float hf;
          W0h[e] = bf16hi(p0, &hf);
          W0l[e] = bf16s(p0 - hf);
          W1h[e] = bf16hi(p1, &hf);
          W1l[e] = bf16s(p1 - hf);
        }
        const bh8 A0 = *reinterpret_cast<const bh8*>(&a0c);
        const bh8 A1 = *reinterpret_cast<const bh8*>(&a1c);
        f4 g;
        g = MFMA_BF16(A0, W0l, z4, 0, 0, 0);
        g = MFMA_BF16(A0, W0h, g, 0, 0, 0);
        #pragma unroll
        for (int e = 0; e < 4; ++e) inc00[e] += fast_tanh(g[e]);
        g = MFMA_BF16(A0, W1l, z4, 0, 0, 0);
        g = MFMA_BF16(A0, W1h, g, 0, 0, 0);
        #pragma unroll
        for (int e = 0; e < 4; ++e) inc01[e] += fast_tanh(g[e]);
        g = MFMA_BF16(A1, W0l, z4, 0, 0, 0);
        g = MFMA_BF16(A1, W0h, g, 0, 0, 0);
        #pragma unroll
        for (int e = 0; e < 4; ++e) inc10[e] += fast_tanh(g[e]);
        g = MFMA_BF16(A1, W1l, z4, 0, 0, 0);
        g = MFMA_BF16(A1, W1h, g, 0, 0, 0);
        #pragma unroll
        for (int e = 0; e < 4; ++e) inc11[e] += fast_tanh(g[e]);
        a0c = a0n;
        a1c = a1n;
      }
    }
    #pragma unroll
    for (int e = 0; e < 4; ++e) {
      atomicAdd(&C_lds[lc * 4 + e][lr], inc00[e]);
      atomicAdd(&C_lds[lc * 4 + e][lr + 16], inc01[e]);
      atomicAdd(&C_lds[16 + lc * 4 + e][lr], inc10[e]);
      atomicAdd(&C_lds[16 + lc * 4 + e][lr + 16], inc11[e]);
    }
    __syncthreads();
  }

  float esum = 0.f;
  for (int t = tid; t < n * 16; t += 128) {
    int j = t >> 4, c = t & 15;
    if (c < 15) {
      float a = b1_s[c];
      #pragma unroll
      for (int kc = 0; kc < 8; ++kc) {
        float4 c4 = *reinterpret_cast<const float4*>(&C_lds[j][kc * 4]);
        a = fmaf(c4.x, w1_s[kc * 4 + 0][c], a);
        a = fmaf(c4.y, w1_s[kc * 4 + 1][c], a);
        a = fmaf(c4.z, w1_s[kc * 4 + 2][c], a);
        a = fmaf(c4.w, w1_s[kc * 4 + 3][c], a);
      }
      esum += fast_tanh(a) * w2_s[c];
    }
  }
  #pragma unroll
  for (int off = 32; off; off >>= 1) esum += __shfl_down(esum, off);
  if (l == 0) wsum[wid] = esum;
  __syncthreads();
  if (tid == 0) outg[b] = wsum[0] + wsum[1] + (float)n * b2g[0];
}

// ---------------------------------------------------------------------------
// Fallback (round-1 fused kernel, d_hat in LDS) for ws_size too small.
// ---------------------------------------------------------------------------
__global__ __launch_bounds__(256, 2) void mdtnn_fused(
    const int* __restrict__ Zg, const float* __restrict__ Dg,
    const int* __restrict__ sizesg, const float* __restrict__ embg,
    const float* __restrict__ dfwg, const float* __restrict__ dfbg,
    const float* __restrict__ cfwg, const float* __restrict__ cfbg,
    const float* __restrict__ fcwg, const float* __restrict__ w1g,
    const float* __restrict__ b1g, const float* __restrict__ w2g,
    const float* __restrict__ b2g, float* __restrict__ outg)
{
  const int b = blockIdx.x;
  const int tid = threadIdx.x;
  const int n = sizesg[b];
  const int njt = (n + 5) / 6;

  __shared__ __align__(16) float cx[2][30][32];
  __shared__ __align__(16) float cfw_s[32][32];
  __shared__ __align__(16) float fcw_s[32][32];
  __shared__ __align__(16) float w1_s[32][16];
  __shared__ __align__(16) int4 dh2[30 * 121];
  __shared__ float dfb_s[32];
  __shared__ float cfb_s[32];
  __shared__ float b1_s[16];
  __shared__ float w2_s[16];
  __shared__ float bsum;

  float (*dfwT)[56] = reinterpret_cast<float (*)[56]>(&cx[0][0][0]);

  for (int t = tid; t < 32 * 56; t += 256) {
    int h = t / 56, g = t - h * 56;
    dfwT[h][g] = (h < 30) ? dfwg[g * 30 + h] : 0.f;
  }
  for (int t = tid; t < 1024; t += 256) {
    int h = t >> 5, k = t & 31;
    bool in = (h < 30) && (k < 30);
    cfw_s[h][k] = in ? cfwg[h * 30 + k] : 0.f;
    fcw_s[h][k] = in ? fcwg[h * 30 + k] : 0.f;
  }
  for (int t = tid; t < 512; t += 256) {
    int h = t >> 4, c = t & 15;
    w1_s[h][c] = ((h < 30) && (c < 15)) ? w1g[h * 15 + c] : 0.f;
  }
  if (tid < 32) {
    dfb_s[tid] = (tid < 30) ? dfbg[tid] : 0.f;
    cfb_s[tid] = (tid < 30) ? cfbg[tid] : 0.f;
  }
  if (tid < 16) {
    b1_s[tid] = (tid < 15) ? b1g[tid] : 0.f;
    w2_s[tid] = (tid < 15) ? w2g[tid] : 0.f;
  }
  if (tid == 0) bsum = 0.f;
  __syncthreads();

  {
    const int tasksA = n * njt * 4;
    for (int task = tid; task < tasksA; task += 256) {
      const int ht = task & 3;
      const int tmp = task >> 2;
      const int jt = tmp % njt;
      const int i = tmp / njt;
      const int j0 = jt * 6;
      const float* Dp = Dg + (((size_t)b * 30 + i) * 30 + j0) * 56;
      float acc[6][8];
      #pragma unroll
      for (int jj = 0; jj < 6; ++jj)
        #pragma unroll
        for (int hh = 0; hh < 8; ++hh) acc[jj][hh] = 0.f;
      #pragma unroll 2
      for (int gc = 0; gc < 14; ++gc) {
        float4 dj[6];
        #pragma unroll
        for (int jj = 0; jj < 6; ++jj)
          dj[jj] = *reinterpret_cast<const float4*>(Dp + jj * 56 + gc * 4);
        #pragma unroll
        for (int hh = 0; hh < 8; ++hh) {
          float4 w = *reinterpret_cast<const float4*>(&dfwT[ht * 8 + hh][gc * 4]);
          #pragma unroll
          for (int jj = 0; jj < 6; ++jj) {
            acc[jj][hh] = fmaf(dj[jj].x, w.x, acc[jj][hh]);
            acc[jj][hh] = fmaf(dj[jj].y, w.y, acc[jj][hh]);
            acc[jj][hh] = fmaf(dj[jj].z, w.z, acc[jj][hh]);
            acc[jj][hh] = fmaf(dj[jj].w, w.w, acc[jj][hh]);
          }
        }
      }
      #pragma unroll
      for (int jj = 0; jj < 6; ++jj) {
        int4 pk;
        pk.x = (int)pack2_bf16(acc[jj][0] + dfb_s[ht * 8 + 0], acc[jj][1] + dfb_s[ht * 8 + 1]);
        pk.y = (int)pack2_bf16(acc[jj][2] + dfb_s[ht * 8 + 2], acc[jj][3] + dfb_s[ht * 8 + 3]);
        pk.z = (int)pack2_bf16(acc[jj][4] + dfb_s[ht * 8 + 4], acc[jj][5] + dfb_s[ht * 8 + 5]);
        pk.w = (int)pack2_bf16(acc[jj][6] + dfb_s[ht * 8 + 6], acc[jj][7] + dfb_s[ht * 8 + 7]);
        dh2[i * 121 + ht * 30 + j0 + jj] = pk;
      }
    }
  }
  __syncthreads();

  for (int t = tid; t < n * 32; t += 256) {
    int i = t >> 5, h = t & 31;
    int z = Zg[b * 30 + i];
    cx[0][i][h] = (h < 30) ? embg[z * 30 + h] : 0.f;
  }
  __syncthreads();

  for (int it = 0; it < 3; ++it) {
    for (int task = tid; task < n * 4; task += 256) {
      int i = task >> 2, kt = task & 3;
      float acc[8];
      #pragma unroll
      for (int kk = 0; kk < 8; ++kk) acc[kk] = 0.f;
      #pragma unroll
      for (int hc = 0; hc < 8; ++hc) {
        float4 c4 = *reinterpret_cast<const float4*>(&cx[0][i][hc * 4]);
        float cv[4] = {c4.x, c4.y, c4.z, c4.w};
        #pragma unroll
        for (int q = 0; q < 4; ++q) {
          float4 wa = *reinterpret_cast<const float4*>(&cfw_s[hc * 4 + q][kt * 8]);
          float4 wb = *reinterpret_cast<const float4*>(&cfw_s[hc * 4 + q][kt * 8 + 4]);
          acc[0] = fmaf(cv[q], wa.x, acc[0]);
          acc[1] = fmaf(cv[q], wa.y, acc[1]);
          acc[2] = fmaf(cv[q], wa.z, acc[2]);
          acc[3] = fmaf(cv[q], wa.w, acc[3]);
          acc[4] = fmaf(cv[q], wb.x, acc[4]);
          acc[5] = fmaf(cv[q], wb.y, acc[5]);
          acc[6] = fmaf(cv[q], wb.z, acc[6]);
          acc[7] = fmaf(cv[q], wb.w, acc[7]);
        }
      }
      #pragma unroll
      for (int kk = 0; kk < 8; ++kk)
        cx[1][i][kt * 8 + kk] = acc[kk] + cfb_s[kt * 8 + kk];
    }
    __syncthreads();

    const int tasksB = n * njt * 4;
    for (int task = tid; task < tasksB; task += 256) {
      const int kt = task & 3;
      const int tmp = task >> 2;
      const int jt = tmp % njt;
      const int i = tmp / njt;
      const int j0 = jt * 6;
      float acc[6][8];
      #pragma unroll
      for (int jj = 0; jj < 6; ++jj)
        #pragma unroll
        for (int kk = 0; kk < 8; ++kk) acc[jj][kk] = 0.f;
      #pragma unroll 1
      for (int hc = 0; hc < 4; ++hc) {
        int4 dv[6];
        #pragma unroll
        for (int jj = 0; jj < 6; ++jj)
          dv[jj] = dh2[i * 121 + hc * 30 + j0 + jj];
        float4 xa = *reinterpret_cast<const float4*>(&cx[1][i][hc * 8]);
        float4 xb = *reinterpret_cast<const float4*>(&cx[1][i][hc * 8 + 4]);
        float xh[8] = {xa.x, xa.y, xa.z, xa.w, xb.x, xb.y, xb.z, xb.w};
        #pragma unroll
        for (int hh = 0; hh < 8; ++hh) {
          float4 wa = *reinterpret_cast<const float4*>(&fcw_s[hc * 8 + hh][kt * 8]);
          float4 wb = *reinterpret_cast<const float4*>(&fcw_s[hc * 8 + hh][kt * 8 + 4]);
          #pragma unroll
          for (int jj = 0; jj < 6; ++jj) {
            unsigned u = reinterpret_cast<const unsigned*>(&dv[jj])[hh >> 1];
            float d = (hh & 1) ? __uint_as_float(u & 0xffff0000u)
                               : __uint_as_float(u << 16);
            float a = d * xh[hh];
            acc[jj][0] = fmaf(a, wa.x, acc[jj][0]);
            acc[jj][1] = fmaf(a, wa.y, acc[jj][1]);
            acc[jj][2] = fmaf(a, wa.z, acc[jj][2]);
            acc[jj][3] = fmaf(a, wa.w, acc[jj][3]);
            acc[jj][4] = fmaf(a, wb.x, acc[jj][4]);
            acc[jj][5] = fmaf(a, wb.y, acc[jj][5]);
            acc[jj][6] = fmaf(a, wb.z, acc[jj][6]);
            acc[jj][7] = fmaf(a, wb.w, acc[jj][7]);
          }
        }
      }
      #pragma unroll
      for (int jj = 0; jj < 6; ++jj)
        #pragma unroll
        for (int kk = 0; kk < 8; ++kk)
          atomicAdd(&cx[0][j0 + jj][kt * 8 + kk], fast_tanh(acc[jj][kk]));
    }
    __syncthreads();
  }

  for (int t = tid; t < n * 16; t += 256) {
    int j = t >> 4, c = t & 15;
    if (c < 15) {
      float acc = 0.f;
      #pragma unroll
      for (int hc = 0; hc < 8; ++hc) {
        float4 c4 = *reinterpret_cast<const float4*>(&cx[0][j][hc * 4]);
        acc = fmaf(c4.x, w1_s[hc * 4 + 0][c], acc);
        acc = fmaf(c4.y, w1_s[hc * 4 + 1][c], acc);
        acc = fmaf(c4.z, w1_s[hc * 4 + 2][c], acc);
        acc = fmaf(c4.w, w1_s[hc * 4 + 3][c], acc);
      }
      atomicAdd(&bsum, fast_tanh(acc + b1_s[c]) * w2_s[c]);
    }
  }
  __syncthreads();
  if (tid == 0) outg[b] = bsum + (float)n * b2g[0];
}

extern "C" void kernel_launch(void* const* d_in, const int* in_sizes, int n_in,
                              void* d_out, int out_size, void* d_ws, size_t ws_size,
                              hipStream_t stream) {
  (void)in_sizes; (void)n_in;
  const int*   Z   = (const int*)d_in[0];
  const float* D   = (const float*)d_in[1];
  const int*   sz  = (const int*)d_in[2];
  const float* emb = (const float*)d_in[3];
  const float* dfw = (const float*)d_in[4];
  const float* dfb = (const float*)d_in[5];
  const float* cfw = (const float*)d_in[6];
  const float* cfb = (const float*)d_in[7];
  const float* fcw = (const float*)d_in[8];
  const float* w1  = (const float*)d_in[9];
  const float* b1  = (const float*)d_in[10];
  const float* w2  = (const float*)d_in[11];
  const float* b2  = (const float*)d_in[12];
  float* out = (float*)d_out;
  const int B = out_size;  // 2048

  const size_t need = (size_t)B * 30 * 30 * 64;  // 118 MB d_hat [b][i][j][h32] bf16
  if (ws_size >= need) {
    mdtnn_phA_mfma<<<dim3(B), dim3(256), 0, stream>>>(D, sz, dfw, dfb, (uint2*)d_ws);
    mdtnn_phB<<<dim3(B), dim3(128), 0, stream>>>(Z, sz, emb, cfw, cfb, fcw,
                                                 w1, b1, w2, b2,
                                                 (const unsigned*)d_ws, out);
  } else {
    mdtnn_fused<<<dim3(B), dim3(256), 0, stream>>>(Z, D, sz, emb, dfw, dfb, cfw, cfb,
                                                   fcw, w1, b1, w2, b2, out);
  }
}